// Round 7
// baseline (453.313 us; speedup 1.0000x reference)
//
#include <hip/hip_runtime.h>
#include <hip/hip_bf16.h>

#define NN 100000
#define NE 3200000
#define FIN 128
#define FH 64
#define FO 64
#define NG 128
#define NP 98        // partitions of 1024 nodes (98*1024 = 100352 >= NN)
#define PSH 10       // partition shift
#define ECAP 36000   // max edges per partition (expect 32768 +/- 181)

typedef unsigned short ushort_t;

__device__ __forceinline__ float bf2f(ushort_t u) {
  unsigned v = ((unsigned)u) << 16;
  float f;
  __builtin_memcpy(&f, &v, 4);
  return f;
}
__device__ __forceinline__ ushort_t f2bf(float f) {
  __hip_bfloat16 b = __float2bfloat16(f);
  ushort_t u;
  __builtin_memcpy(&u, &b, 2);
  return u;
}

// ---------------- init: zero partition counters + output ----------------
__global__ void k_init(int* __restrict__ pcnt, int* __restrict__ pcur,
                       float* __restrict__ out) {
  int i = blockIdx.x * blockDim.x + threadIdx.x;
  if (i < NP) { pcnt[i] = 0; pcur[i] = 0; }
  if (i < NG * (FO + FH)) out[i] = 0.0f;
}

// ---------------- partition histogram ----------------
__global__ __launch_bounds__(256) void k_phist(const int* __restrict__ ei,
                                               int* __restrict__ pcnt) {
  __shared__ int lh[NP];
  int tid = threadIdx.x;
  if (tid < NP) lh[tid] = 0;
  __syncthreads();
  const int EPB = NE / 256;  // 12500
  int base = blockIdx.x * EPB;
  for (int i = tid; i < EPB; i += 256) atomicAdd(&lh[ei[NE + base + i] >> PSH], 1);
  __syncthreads();
  if (tid < NP && lh[tid]) atomicAdd(&pcnt[tid], lh[tid]);
}

// ---------------- tiny serial scan of 98 partition counts ----------------
__global__ void k_pscan(const int* __restrict__ pcnt, int* __restrict__ poff) {
  if (threadIdx.x == 0) {
    int run = 0;
    for (int i = 0; i < NP; ++i) { poff[i] = run; run += pcnt[i]; }
    poff[NP] = run;  // == NE
  }
}

// ---------------- two-phase block-local scatter into partitions ----------------
__global__ __launch_bounds__(256) void k_pscatter(const int* __restrict__ ei,
                                                  const int* __restrict__ poff,
                                                  int* __restrict__ pcur,
                                                  int* __restrict__ part_e) {
  __shared__ int lbase[NP];
  __shared__ int lcur[NP];
  const int EPB = NE / 256;  // 12500
  int base = blockIdx.x * EPB;
  int tid = threadIdx.x;
  if (tid < NP) { lbase[tid] = 0; lcur[tid] = 0; }
  __syncthreads();
  for (int i = tid; i < EPB; i += 256) atomicAdd(&lbase[ei[NE + base + i] >> PSH], 1);
  __syncthreads();
  if (tid < NP) {
    int c = lbase[tid];
    lbase[tid] = c ? (poff[tid] + atomicAdd(&pcur[tid], c)) : 0;
  }
  __syncthreads();
  for (int i = tid; i < EPB; i += 256) {
    int s = ei[base + i];
    int d = ei[NE + base + i];
    int p = d >> PSH;
    int pos = atomicAdd(&lcur[p], 1);
    part_e[lbase[p] + pos] = (s << PSH) | (d & 1023);
  }
}

// ---------------- per-partition LDS counting sort -> CSR + rowptr + dinv ----------------
__global__ __launch_bounds__(1024) void k_psort(const int* __restrict__ part_e,
                                                const int* __restrict__ poff,
                                                int* __restrict__ rowptr,
                                                float* __restrict__ dinv,
                                                int* __restrict__ csr_src) {
  __shared__ int ew[ECAP];     // 144 KB
  __shared__ int cnt[1024];
  __shared__ int pref[1024];
  int p = blockIdx.x, tid = threadIdx.x;
  int beg = poff[p], end = poff[p + 1];
  int m = end - beg;
  for (int i = tid; i < m; i += 1024) ew[i] = part_e[beg + i];
  cnt[tid] = 0;
  __syncthreads();
  for (int i = tid; i < m; i += 1024) atomicAdd(&cnt[ew[i] & 1023], 1);
  __syncthreads();
  pref[tid] = cnt[tid];
  __syncthreads();
  for (int d = 1; d < 1024; d <<= 1) {
    int t = (tid >= d) ? pref[tid - d] : 0;
    __syncthreads();
    pref[tid] += t;
    __syncthreads();
  }
  int excl = pref[tid] - cnt[tid];
  int n = p * 1024 + tid;
  if (n < NN) {
    rowptr[n] = beg + excl;
    dinv[n] = rsqrtf((float)cnt[tid] + 1.0f);
  }
  if (p == 0 && tid == 0) rowptr[NN] = NE;
  __syncthreads();
  pref[tid] = excl;
  __syncthreads();
  for (int i = tid; i < m; i += 1024) {
    int w = ew[i];
    int pos = atomicAdd(&pref[w & 1023], 1);
    csr_src[beg + pos] = w >> PSH;
  }
}

// ---------------- root indices + graph node counts via binary search ----------------
__global__ __launch_bounds__(128) void k_root(const int* __restrict__ batch,
                                              int* __restrict__ root_idx,
                                              int* __restrict__ gcnt) {
  int g = threadIdx.x;
  if (g >= NG) return;
  int lo = 0, hi = NN;
  while (lo < hi) { int m = (lo + hi) >> 1; if (batch[m] < g) lo = m + 1; else hi = m; }
  int a = lo;
  lo = a; hi = NN;
  while (lo < hi) { int m = (lo + hi) >> 1; if (batch[m] < g + 1) lo = m + 1; else hi = m; }
  int b = lo;
  gcnt[g] = b - a;
  root_idx[g] = (b > a) ? a : (NN - 1);
}

// ---------------- GEMM1: ps1 = bf16((x @ W1) * dinv[n]) ----------------
__global__ __launch_bounds__(256) void k_gemm1(const float* __restrict__ x,
                                               const float* __restrict__ W1,
                                               const float* __restrict__ dinv,
                                               ushort_t* __restrict__ ps) {
  __shared__ float Ws[FIN * FH];   // 32 KB
  __shared__ float Xs[16 * FIN];   // 8 KB
  int tid = threadIdx.x;
  for (int i = tid; i < FIN * FH; i += 256) Ws[i] = W1[i];
  long n0 = (long)blockIdx.x * 16;
  const float4* xg = (const float4*)(x + n0 * FIN);
  float4* xs4 = (float4*)Xs;
  for (int i = tid; i < 16 * FIN / 4; i += 256) xs4[i] = xg[i];
  __syncthreads();
  int f = tid & 63;
  int nl = tid >> 6;
  int b = nl * 4;
  float acc0 = 0.f, acc1 = 0.f, acc2 = 0.f, acc3 = 0.f;
  #pragma unroll 4
  for (int i = 0; i < FIN; i += 4) {
    float4 x0 = *(const float4*)&Xs[(b + 0) * FIN + i];
    float4 x1 = *(const float4*)&Xs[(b + 1) * FIN + i];
    float4 x2 = *(const float4*)&Xs[(b + 2) * FIN + i];
    float4 x3 = *(const float4*)&Xs[(b + 3) * FIN + i];
    float w0 = Ws[(i + 0) * FH + f];
    float w1 = Ws[(i + 1) * FH + f];
    float w2 = Ws[(i + 2) * FH + f];
    float w3 = Ws[(i + 3) * FH + f];
    acc0 += x0.x * w0 + x0.y * w1 + x0.z * w2 + x0.w * w3;
    acc1 += x1.x * w0 + x1.y * w1 + x1.z * w2 + x1.w * w3;
    acc2 += x2.x * w0 + x2.y * w1 + x2.z * w2 + x2.w * w3;
    acc3 += x3.x * w0 + x3.y * w1 + x3.z * w2 + x3.w * w3;
  }
  ps[(n0 + b + 0) * FH + f] = f2bf(acc0 * dinv[n0 + b + 0]);
  ps[(n0 + b + 1) * FH + f] = f2bf(acc1 * dinv[n0 + b + 1]);
  ps[(n0 + b + 2) * FH + f] = f2bf(acc2 * dinv[n0 + b + 2]);
  ps[(n0 + b + 3) * FH + f] = f2bf(acc3 * dinv[n0 + b + 3]);
}

// ---------------- per-graph root projection: relu(x[root]) @ W2[64:192,:] ----------------
__global__ __launch_bounds__(64) void k_rootproj(const float* __restrict__ x,
                                                 const float* __restrict__ W2,
                                                 const int* __restrict__ root_idx,
                                                 float* __restrict__ rp) {
  __shared__ float xr[FIN];
  int g = blockIdx.x;
  int t = threadIdx.x;
  long r = root_idx[g];
  xr[t]      = fmaxf(x[r * FIN + t], 0.0f);
  xr[t + 64] = fmaxf(x[r * FIN + t + 64], 0.0f);
  __syncthreads();
  float acc = 0.0f;
  #pragma unroll 8
  for (int i = 0; i < FIN; ++i) acc += xr[i] * W2[(FH + i) * FO + t];
  rp[g * FO + t] = acc;
}

// ---------------- per-node aggregation (wave per node, 4-edge-wide gather) ----------------
// 16 lanes per edge-row, ushort4 (8B) per lane; cross-group shfl_xor reduce.
// ps prescaled by dinv[src]; out = bf16(dinv[n]*(ps[n]+sum ps[src]) + bias) [relu]
template <int RELU>
__global__ __launch_bounds__(256) void k_agg(const ushort_t* __restrict__ ps,
                                             const float* __restrict__ dinv,
                                             const int* __restrict__ rowptr,
                                             const int* __restrict__ csr_src,
                                             const float* __restrict__ bias,
                                             ushort_t* __restrict__ outb) {
  int tid = threadIdx.x;
  int wave = tid >> 6, lane = tid & 63;
  int n = blockIdx.x * 4 + wave;   // grid is exactly NN/4 blocks
  int grp = lane >> 4, q = lane & 15;
  int beg = rowptr[n], end = rowptr[n + 1];
  float a0 = 0.f, a1 = 0.f, a2 = 0.f, a3 = 0.f;
  for (int i = beg + grp; i < end; i += 4) {
    int s = __builtin_nontemporal_load(&csr_src[i]);
    ushort4 v = *(const ushort4*)(ps + ((long)s << 6) + (q << 2));
    a0 += bf2f(v.x); a1 += bf2f(v.y); a2 += bf2f(v.z); a3 += bf2f(v.w);
  }
  a0 += __shfl_xor(a0, 16); a1 += __shfl_xor(a1, 16);
  a2 += __shfl_xor(a2, 16); a3 += __shfl_xor(a3, 16);
  a0 += __shfl_xor(a0, 32); a1 += __shfl_xor(a1, 32);
  a2 += __shfl_xor(a2, 32); a3 += __shfl_xor(a3, 32);
  // self term (once, after reduce)
  ushort4 sv = *(const ushort4*)(ps + ((long)n << 6) + (q << 2));
  a0 += bf2f(sv.x); a1 += bf2f(sv.y); a2 += bf2f(sv.z); a3 += bf2f(sv.w);
  float dn = dinv[n];
  const float4 b4 = *(const float4*)(bias + (q << 2));
  a0 = dn * a0 + b4.x; a1 = dn * a1 + b4.y;
  a2 = dn * a2 + b4.z; a3 = dn * a3 + b4.w;
  if (RELU) {
    a0 = fmaxf(a0, 0.f); a1 = fmaxf(a1, 0.f);
    a2 = fmaxf(a2, 0.f); a3 = fmaxf(a3, 0.f);
  }
  if (grp == 0) {
    ushort4 o;
    o.x = f2bf(a0); o.y = f2bf(a1); o.z = f2bf(a2); o.w = f2bf(a3);
    *(ushort4*)(outb + ((long)n << 6) + (q << 2)) = o;
  }
}

// ---------------- GEMM2: ps2 = bf16((relu(h1) @ W2[0:64,:] + rp[batch]) * dinv) ----------------
__global__ __launch_bounds__(256) void k_gemm2(const ushort_t* __restrict__ h1,
                                               const float* __restrict__ W2,
                                               const float* __restrict__ rp,
                                               const int* __restrict__ batch,
                                               const float* __restrict__ dinv,
                                               ushort_t* __restrict__ ps2) {
  __shared__ float Ws[FH * FO];   // 16 KB
  __shared__ float Hs[16 * FH];   // 4 KB
  int tid = threadIdx.x;
  for (int i = tid; i < FH * FO; i += 256) Ws[i] = W2[i];
  long n0 = (long)blockIdx.x * 16;
  {
    // stage relu(bf16 h1) -> fp32 LDS, vectorized
    ushort4 v = *(const ushort4*)(h1 + n0 * FH + tid * 4);
    float4 f;
    f.x = fmaxf(bf2f(v.x), 0.f); f.y = fmaxf(bf2f(v.y), 0.f);
    f.z = fmaxf(bf2f(v.z), 0.f); f.w = fmaxf(bf2f(v.w), 0.f);
    *(float4*)&Hs[tid * 4] = f;
  }
  __syncthreads();
  int f = tid & 63;
  int nl = tid >> 6;
  int b = nl * 4;
  float acc0 = rp[(long)batch[n0 + b + 0] * FO + f];
  float acc1 = rp[(long)batch[n0 + b + 1] * FO + f];
  float acc2 = rp[(long)batch[n0 + b + 2] * FO + f];
  float acc3 = rp[(long)batch[n0 + b + 3] * FO + f];
  #pragma unroll 4
  for (int j = 0; j < FH; j += 4) {
    float4 h0 = *(const float4*)&Hs[(b + 0) * FH + j];
    float4 h1v = *(const float4*)&Hs[(b + 1) * FH + j];
    float4 h2v = *(const float4*)&Hs[(b + 2) * FH + j];
    float4 h3 = *(const float4*)&Hs[(b + 3) * FH + j];
    float w0 = Ws[(j + 0) * FO + f];
    float w1 = Ws[(j + 1) * FO + f];
    float w2 = Ws[(j + 2) * FO + f];
    float w3 = Ws[(j + 3) * FO + f];
    acc0 += h0.x * w0 + h0.y * w1 + h0.z * w2 + h0.w * w3;
    acc1 += h1v.x * w0 + h1v.y * w1 + h1v.z * w2 + h1v.w * w3;
    acc2 += h2v.x * w0 + h2v.y * w1 + h2v.z * w2 + h2v.w * w3;
    acc3 += h3.x * w0 + h3.y * w1 + h3.z * w2 + h3.w * w3;
  }
  ps2[(n0 + b + 0) * FH + f] = f2bf(acc0 * dinv[n0 + b + 0]);
  ps2[(n0 + b + 1) * FH + f] = f2bf(acc1 * dinv[n0 + b + 1]);
  ps2[(n0 + b + 2) * FH + f] = f2bf(acc2 * dinv[n0 + b + 2]);
  ps2[(n0 + b + 3) * FH + f] = f2bf(acc3 * dinv[n0 + b + 3]);
}

// ---------------- mean-pool: segment sums of r (bf16) over batch ----------------
__global__ __launch_bounds__(64) void k_pool(const ushort_t* __restrict__ r,
                                             const int* __restrict__ batch,
                                             float* __restrict__ out) {
  const int PC = 100;
  int lane = threadIdx.x;
  long n0 = (long)blockIdx.x * PC;
  long n1 = n0 + PC;
  if (n1 > NN) n1 = NN;
  if (n0 >= NN) return;
  float acc = 0.0f;
  int cur = batch[n0];
  for (long n = n0; n < n1; ++n) {
    int g = batch[n];
    if (g != cur) {
      atomicAdd(&out[(long)cur * (FO + FH) + lane], acc);
      acc = 0.0f;
      cur = g;
    }
    acc += bf2f(r[n * FH + lane]);
  }
  atomicAdd(&out[(long)cur * (FO + FH) + lane], acc);
}

// ---------------- finalize: divide by count; fill root2 half ----------------
__global__ void k_final(float* __restrict__ out, const int* __restrict__ gcnt,
                        const int* __restrict__ root_idx, const ushort_t* __restrict__ h1full) {
  int i = blockIdx.x * blockDim.x + threadIdx.x;
  if (i >= NG * FO) return;
  int g = i >> 6, f = i & 63;
  int c = gcnt[g];
  float inv = 1.0f / fmaxf((float)c, 1.0f);
  out[g * (FO + FH) + f] *= inv;
  out[g * (FO + FH) + FO + f] = (c > 0) ? bf2f(h1full[(long)root_idx[g] * FH + f]) : 0.0f;
}

extern "C" void kernel_launch(void* const* d_in, const int* in_sizes, int n_in,
                              void* d_out, int out_size, void* d_ws, size_t ws_size,
                              hipStream_t stream) {
  const float* x   = (const float*)d_in[0];
  const int*   ei  = (const int*)d_in[1];
  const int*   bat = (const int*)d_in[2];
  const float* W1  = (const float*)d_in[3];
  const float* b1  = (const float*)d_in[4];
  const float* W2  = (const float*)d_in[5];
  const float* b2  = (const float*)d_in[6];
  float* out = (float*)d_out;

  char* p = (char*)d_ws;
  auto carve = [&](size_t bytes) -> void* {
    char* q = p;
    p += (bytes + 511) & ~size_t(511);
    return (void*)q;
  };
  float* dinv    = (float*)carve((size_t)NN * 4);
  int*   pcnt    = (int*)carve((size_t)NP * 4);
  int*   poff    = (int*)carve((size_t)(NP + 1) * 4);
  int*   pcur    = (int*)carve((size_t)NP * 4);
  int*   part_e  = (int*)carve((size_t)NE * 4);
  int*   rowptr  = (int*)carve((size_t)(NN + 1) * 4);
  int*   csr_src = (int*)carve((size_t)NE * 4);
  ushort_t* psA  = (ushort_t*)carve((size_t)NN * FH * 2);  // ps1 bf16
  ushort_t* psB  = (ushort_t*)carve((size_t)NN * FH * 2);  // ps2 bf16
  ushort_t* bufB = (ushort_t*)carve((size_t)NN * FH * 2);  // h1 bf16
  ushort_t* bufD = (ushort_t*)carve((size_t)NN * FH * 2);  // r  bf16
  int*   root_i  = (int*)carve((size_t)NG * 4);
  int*   gcnt    = (int*)carve((size_t)NG * 4);
  float* rp      = (float*)carve((size_t)NG * FO * 4);

  k_init<<<64, 256, 0, stream>>>(pcnt, pcur, out);
  k_phist<<<256, 256, 0, stream>>>(ei, pcnt);
  k_pscan<<<1, 64, 0, stream>>>(pcnt, poff);
  k_pscatter<<<256, 256, 0, stream>>>(ei, poff, pcur, part_e);
  k_psort<<<NP, 1024, 0, stream>>>(part_e, poff, rowptr, dinv, csr_src);
  k_gemm1<<<NN / 16, 256, 0, stream>>>(x, W1, dinv, psA);
  k_root<<<1, 128, 0, stream>>>(bat, root_i, gcnt);
  k_rootproj<<<NG, 64, 0, stream>>>(x, W2, root_i, rp);
  k_agg<0><<<NN / 4, 256, 0, stream>>>(psA, dinv, rowptr, csr_src, b1, bufB);
  k_gemm2<<<NN / 16, 256, 0, stream>>>(bufB, W2, rp, bat, dinv, psB);
  k_agg<1><<<NN / 4, 256, 0, stream>>>(psB, dinv, rowptr, csr_src, b2, bufD);
  k_pool<<<(NN + 99) / 100, 64, 0, stream>>>(bufD, bat, out);
  k_final<<<(NG * FO + 255) / 256, 256, 0, stream>>>(out, gcnt, root_i, bufB);
}

// Round 8
// 368.922 us; speedup vs baseline: 1.2288x; 1.2288x over previous
//
#include <hip/hip_runtime.h>
#include <hip/hip_bf16.h>

#define NN 100000
#define NE 3200000
#define FIN 128
#define FH 64
#define FO 64
#define NG 128
#define NP 98        // partitions of 1024 nodes (98*1024 = 100352 >= NN)
#define PSH 10       // partition shift
#define ECAP 36000   // max edges per partition (expect 32768 +/- 181)

typedef unsigned short ushort_t;

__device__ __forceinline__ float bf2f(ushort_t u) {
  unsigned v = ((unsigned)u) << 16;
  float f;
  __builtin_memcpy(&f, &v, 4);
  return f;
}
__device__ __forceinline__ ushort_t f2bf(float f) {
  __hip_bfloat16 b = __float2bfloat16(f);
  ushort_t u;
  __builtin_memcpy(&u, &b, 2);
  return u;
}

// ---------------- init: zero partition counters + output ----------------
__global__ void k_init(int* __restrict__ pcnt, int* __restrict__ pcur,
                       float* __restrict__ out) {
  int i = blockIdx.x * blockDim.x + threadIdx.x;
  if (i < NP) { pcnt[i] = 0; pcur[i] = 0; }
  if (i < NG * (FO + FH)) out[i] = 0.0f;
}

// ---------------- partition histogram ----------------
__global__ __launch_bounds__(256) void k_phist(const int* __restrict__ ei,
                                               int* __restrict__ pcnt) {
  __shared__ int lh[NP];
  int tid = threadIdx.x;
  if (tid < NP) lh[tid] = 0;
  __syncthreads();
  const int EPB = NE / 256;  // 12500
  int base = blockIdx.x * EPB;
  for (int i = tid; i < EPB; i += 256) atomicAdd(&lh[ei[NE + base + i] >> PSH], 1);
  __syncthreads();
  if (tid < NP && lh[tid]) atomicAdd(&pcnt[tid], lh[tid]);
}

// ---------------- tiny serial scan of 98 partition counts ----------------
__global__ void k_pscan(const int* __restrict__ pcnt, int* __restrict__ poff) {
  if (threadIdx.x == 0) {
    int run = 0;
    for (int i = 0; i < NP; ++i) { poff[i] = run; run += pcnt[i]; }
    poff[NP] = run;  // == NE
  }
}

// ---------------- two-phase block-local scatter into partitions ----------------
__global__ __launch_bounds__(256) void k_pscatter(const int* __restrict__ ei,
                                                  const int* __restrict__ poff,
                                                  int* __restrict__ pcur,
                                                  int* __restrict__ part_e) {
  __shared__ int lbase[NP];
  __shared__ int lcur[NP];
  const int EPB = NE / 256;  // 12500
  int base = blockIdx.x * EPB;
  int tid = threadIdx.x;
  if (tid < NP) { lbase[tid] = 0; lcur[tid] = 0; }
  __syncthreads();
  for (int i = tid; i < EPB; i += 256) atomicAdd(&lbase[ei[NE + base + i] >> PSH], 1);
  __syncthreads();
  if (tid < NP) {
    int c = lbase[tid];
    lbase[tid] = c ? (poff[tid] + atomicAdd(&pcur[tid], c)) : 0;
  }
  __syncthreads();
  for (int i = tid; i < EPB; i += 256) {
    int s = ei[base + i];
    int d = ei[NE + base + i];
    int p = d >> PSH;
    int pos = atomicAdd(&lcur[p], 1);
    part_e[lbase[p] + pos] = (s << PSH) | (d & 1023);
  }
}

// ---------------- per-partition LDS counting sort -> CSR + rowptr + dinv ----------------
__global__ __launch_bounds__(1024) void k_psort(const int* __restrict__ part_e,
                                                const int* __restrict__ poff,
                                                int* __restrict__ rowptr,
                                                float* __restrict__ dinv,
                                                int* __restrict__ csr_src) {
  __shared__ int ew[ECAP];     // 144 KB
  __shared__ int cnt[1024];
  __shared__ int pref[1024];
  int p = blockIdx.x, tid = threadIdx.x;
  int beg = poff[p], end = poff[p + 1];
  int m = end - beg;
  for (int i = tid; i < m; i += 1024) ew[i] = part_e[beg + i];
  cnt[tid] = 0;
  __syncthreads();
  for (int i = tid; i < m; i += 1024) atomicAdd(&cnt[ew[i] & 1023], 1);
  __syncthreads();
  pref[tid] = cnt[tid];
  __syncthreads();
  for (int d = 1; d < 1024; d <<= 1) {
    int t = (tid >= d) ? pref[tid - d] : 0;
    __syncthreads();
    pref[tid] += t;
    __syncthreads();
  }
  int excl = pref[tid] - cnt[tid];
  int n = p * 1024 + tid;
  if (n < NN) {
    rowptr[n] = beg + excl;
    dinv[n] = rsqrtf((float)cnt[tid] + 1.0f);
  }
  if (p == 0 && tid == 0) rowptr[NN] = NE;
  __syncthreads();
  pref[tid] = excl;
  __syncthreads();
  for (int i = tid; i < m; i += 1024) {
    int w = ew[i];
    int pos = atomicAdd(&pref[w & 1023], 1);
    csr_src[beg + pos] = w >> PSH;
  }
}

// ---------------- root indices + graph node counts via binary search ----------------
__global__ __launch_bounds__(128) void k_root(const int* __restrict__ batch,
                                              int* __restrict__ root_idx,
                                              int* __restrict__ gcnt) {
  int g = threadIdx.x;
  if (g >= NG) return;
  int lo = 0, hi = NN;
  while (lo < hi) { int m = (lo + hi) >> 1; if (batch[m] < g) lo = m + 1; else hi = m; }
  int a = lo;
  lo = a; hi = NN;
  while (lo < hi) { int m = (lo + hi) >> 1; if (batch[m] < g + 1) lo = m + 1; else hi = m; }
  int b = lo;
  gcnt[g] = b - a;
  root_idx[g] = (b > a) ? a : (NN - 1);
}

// ---------------- GEMM1: ps1 = bf16((x @ W1) * dinv[n]) ----------------
__global__ __launch_bounds__(256) void k_gemm1(const float* __restrict__ x,
                                               const float* __restrict__ W1,
                                               const float* __restrict__ dinv,
                                               ushort_t* __restrict__ ps) {
  __shared__ float Ws[FIN * FH];   // 32 KB
  __shared__ float Xs[16 * FIN];   // 8 KB
  int tid = threadIdx.x;
  for (int i = tid; i < FIN * FH; i += 256) Ws[i] = W1[i];
  long n0 = (long)blockIdx.x * 16;
  const float4* xg = (const float4*)(x + n0 * FIN);
  float4* xs4 = (float4*)Xs;
  for (int i = tid; i < 16 * FIN / 4; i += 256) xs4[i] = xg[i];
  __syncthreads();
  int f = tid & 63;
  int nl = tid >> 6;
  int b = nl * 4;
  float acc0 = 0.f, acc1 = 0.f, acc2 = 0.f, acc3 = 0.f;
  #pragma unroll 4
  for (int i = 0; i < FIN; i += 4) {
    float4 x0 = *(const float4*)&Xs[(b + 0) * FIN + i];
    float4 x1 = *(const float4*)&Xs[(b + 1) * FIN + i];
    float4 x2 = *(const float4*)&Xs[(b + 2) * FIN + i];
    float4 x3 = *(const float4*)&Xs[(b + 3) * FIN + i];
    float w0 = Ws[(i + 0) * FH + f];
    float w1 = Ws[(i + 1) * FH + f];
    float w2 = Ws[(i + 2) * FH + f];
    float w3 = Ws[(i + 3) * FH + f];
    acc0 += x0.x * w0 + x0.y * w1 + x0.z * w2 + x0.w * w3;
    acc1 += x1.x * w0 + x1.y * w1 + x1.z * w2 + x1.w * w3;
    acc2 += x2.x * w0 + x2.y * w1 + x2.z * w2 + x2.w * w3;
    acc3 += x3.x * w0 + x3.y * w1 + x3.z * w2 + x3.w * w3;
  }
  ps[(n0 + b + 0) * FH + f] = f2bf(acc0 * dinv[n0 + b + 0]);
  ps[(n0 + b + 1) * FH + f] = f2bf(acc1 * dinv[n0 + b + 1]);
  ps[(n0 + b + 2) * FH + f] = f2bf(acc2 * dinv[n0 + b + 2]);
  ps[(n0 + b + 3) * FH + f] = f2bf(acc3 * dinv[n0 + b + 3]);
}

// ---------------- per-graph root projection: relu(x[root]) @ W2[64:192,:] ----------------
__global__ __launch_bounds__(64) void k_rootproj(const float* __restrict__ x,
                                                 const float* __restrict__ W2,
                                                 const int* __restrict__ root_idx,
                                                 float* __restrict__ rp) {
  __shared__ float xr[FIN];
  int g = blockIdx.x;
  int t = threadIdx.x;
  long r = root_idx[g];
  xr[t]      = fmaxf(x[r * FIN + t], 0.0f);
  xr[t + 64] = fmaxf(x[r * FIN + t + 64], 0.0f);
  __syncthreads();
  float acc = 0.0f;
  #pragma unroll 8
  for (int i = 0; i < FIN; ++i) acc += xr[i] * W2[(FH + i) * FO + t];
  rp[g * FO + t] = acc;
}

// ---------------- per-node aggregation (wave per node, lane=feature, 8-deep MLP) ----------------
// ps prescaled by dinv[src]; out = bf16(dinv[n]*(ps[n]+sum ps[src]) + bias) [relu]
template <int RELU>
__global__ __launch_bounds__(256) void k_agg(const ushort_t* __restrict__ ps,
                                             const float* __restrict__ dinv,
                                             const int* __restrict__ rowptr,
                                             const int* __restrict__ csr_src,
                                             const float* __restrict__ bias,
                                             ushort_t* __restrict__ outb) {
  int wave = threadIdx.x >> 6;
  int lane = threadIdx.x & 63;
  int n = blockIdx.x * 4 + wave;   // grid exactly NN/4
  float acc = bf2f(ps[((long)n << 6) + lane]);  // self term (prescaled)
  int beg = rowptr[n], end = rowptr[n + 1];
  int i = beg;
  for (; i + 8 <= end; i += 8) {
    int s0 = csr_src[i + 0];
    int s1 = csr_src[i + 1];
    int s2 = csr_src[i + 2];
    int s3 = csr_src[i + 3];
    int s4 = csr_src[i + 4];
    int s5 = csr_src[i + 5];
    int s6 = csr_src[i + 6];
    int s7 = csr_src[i + 7];
    float v0 = bf2f(ps[((long)s0 << 6) + lane]);
    float v1 = bf2f(ps[((long)s1 << 6) + lane]);
    float v2 = bf2f(ps[((long)s2 << 6) + lane]);
    float v3 = bf2f(ps[((long)s3 << 6) + lane]);
    float v4 = bf2f(ps[((long)s4 << 6) + lane]);
    float v5 = bf2f(ps[((long)s5 << 6) + lane]);
    float v6 = bf2f(ps[((long)s6 << 6) + lane]);
    float v7 = bf2f(ps[((long)s7 << 6) + lane]);
    acc += v0; acc += v1; acc += v2; acc += v3;
    acc += v4; acc += v5; acc += v6; acc += v7;
  }
  for (; i + 4 <= end; i += 4) {
    int s0 = csr_src[i + 0];
    int s1 = csr_src[i + 1];
    int s2 = csr_src[i + 2];
    int s3 = csr_src[i + 3];
    float v0 = bf2f(ps[((long)s0 << 6) + lane]);
    float v1 = bf2f(ps[((long)s1 << 6) + lane]);
    float v2 = bf2f(ps[((long)s2 << 6) + lane]);
    float v3 = bf2f(ps[((long)s3 << 6) + lane]);
    acc += v0; acc += v1; acc += v2; acc += v3;
  }
  for (; i < end; ++i) acc += bf2f(ps[((long)csr_src[i] << 6) + lane]);
  float val = dinv[n] * acc + bias[lane];
  if (RELU) val = fmaxf(val, 0.0f);
  outb[((long)n << 6) + lane] = f2bf(val);
}

// ---------------- GEMM2: ps2 = bf16((relu(h1) @ W2[0:64,:] + rp[batch]) * dinv) ----------------
__global__ __launch_bounds__(256) void k_gemm2(const ushort_t* __restrict__ h1,
                                               const float* __restrict__ W2,
                                               const float* __restrict__ rp,
                                               const int* __restrict__ batch,
                                               const float* __restrict__ dinv,
                                               ushort_t* __restrict__ ps2) {
  __shared__ float Ws[FH * FO];   // 16 KB
  __shared__ float Hs[16 * FH];   // 4 KB
  int tid = threadIdx.x;
  for (int i = tid; i < FH * FO; i += 256) Ws[i] = W2[i];
  long n0 = (long)blockIdx.x * 16;
  {
    ushort4 v = *(const ushort4*)(h1 + n0 * FH + tid * 4);
    float4 f;
    f.x = fmaxf(bf2f(v.x), 0.f); f.y = fmaxf(bf2f(v.y), 0.f);
    f.z = fmaxf(bf2f(v.z), 0.f); f.w = fmaxf(bf2f(v.w), 0.f);
    *(float4*)&Hs[tid * 4] = f;
  }
  __syncthreads();
  int f = tid & 63;
  int nl = tid >> 6;
  int b = nl * 4;
  float acc0 = rp[(long)batch[n0 + b + 0] * FO + f];
  float acc1 = rp[(long)batch[n0 + b + 1] * FO + f];
  float acc2 = rp[(long)batch[n0 + b + 2] * FO + f];
  float acc3 = rp[(long)batch[n0 + b + 3] * FO + f];
  #pragma unroll 4
  for (int j = 0; j < FH; j += 4) {
    float4 h0 = *(const float4*)&Hs[(b + 0) * FH + j];
    float4 h1v = *(const float4*)&Hs[(b + 1) * FH + j];
    float4 h2v = *(const float4*)&Hs[(b + 2) * FH + j];
    float4 h3 = *(const float4*)&Hs[(b + 3) * FH + j];
    float w0 = Ws[(j + 0) * FO + f];
    float w1 = Ws[(j + 1) * FO + f];
    float w2 = Ws[(j + 2) * FO + f];
    float w3 = Ws[(j + 3) * FO + f];
    acc0 += h0.x * w0 + h0.y * w1 + h0.z * w2 + h0.w * w3;
    acc1 += h1v.x * w0 + h1v.y * w1 + h1v.z * w2 + h1v.w * w3;
    acc2 += h2v.x * w0 + h2v.y * w1 + h2v.z * w2 + h2v.w * w3;
    acc3 += h3.x * w0 + h3.y * w1 + h3.z * w2 + h3.w * w3;
  }
  ps2[(n0 + b + 0) * FH + f] = f2bf(acc0 * dinv[n0 + b + 0]);
  ps2[(n0 + b + 1) * FH + f] = f2bf(acc1 * dinv[n0 + b + 1]);
  ps2[(n0 + b + 2) * FH + f] = f2bf(acc2 * dinv[n0 + b + 2]);
  ps2[(n0 + b + 3) * FH + f] = f2bf(acc3 * dinv[n0 + b + 3]);
}

// ---------------- mean-pool: segment sums of r (bf16) over batch ----------------
__global__ __launch_bounds__(64) void k_pool(const ushort_t* __restrict__ r,
                                             const int* __restrict__ batch,
                                             float* __restrict__ out) {
  const int PC = 100;
  int lane = threadIdx.x;
  long n0 = (long)blockIdx.x * PC;
  long n1 = n0 + PC;
  if (n1 > NN) n1 = NN;
  if (n0 >= NN) return;
  float acc = 0.0f;
  int cur = batch[n0];
  for (long n = n0; n < n1; ++n) {
    int g = batch[n];
    if (g != cur) {
      atomicAdd(&out[(long)cur * (FO + FH) + lane], acc);
      acc = 0.0f;
      cur = g;
    }
    acc += bf2f(r[n * FH + lane]);
  }
  atomicAdd(&out[(long)cur * (FO + FH) + lane], acc);
}

// ---------------- finalize: divide by count; fill root2 half ----------------
__global__ void k_final(float* __restrict__ out, const int* __restrict__ gcnt,
                        const int* __restrict__ root_idx, const ushort_t* __restrict__ h1full) {
  int i = blockIdx.x * blockDim.x + threadIdx.x;
  if (i >= NG * FO) return;
  int g = i >> 6, f = i & 63;
  int c = gcnt[g];
  float inv = 1.0f / fmaxf((float)c, 1.0f);
  out[g * (FO + FH) + f] *= inv;
  out[g * (FO + FH) + FO + f] = (c > 0) ? bf2f(h1full[(long)root_idx[g] * FH + f]) : 0.0f;
}

extern "C" void kernel_launch(void* const* d_in, const int* in_sizes, int n_in,
                              void* d_out, int out_size, void* d_ws, size_t ws_size,
                              hipStream_t stream) {
  const float* x   = (const float*)d_in[0];
  const int*   ei  = (const int*)d_in[1];
  const int*   bat = (const int*)d_in[2];
  const float* W1  = (const float*)d_in[3];
  const float* b1  = (const float*)d_in[4];
  const float* W2  = (const float*)d_in[5];
  const float* b2  = (const float*)d_in[6];
  float* out = (float*)d_out;

  char* p = (char*)d_ws;
  auto carve = [&](size_t bytes) -> void* {
    char* q = p;
    p += (bytes + 511) & ~size_t(511);
    return (void*)q;
  };
  float* dinv    = (float*)carve((size_t)NN * 4);
  int*   pcnt    = (int*)carve((size_t)NP * 4);
  int*   poff    = (int*)carve((size_t)(NP + 1) * 4);
  int*   pcur    = (int*)carve((size_t)NP * 4);
  int*   part_e  = (int*)carve((size_t)NE * 4);
  int*   rowptr  = (int*)carve((size_t)(NN + 1) * 4);
  int*   csr_src = (int*)carve((size_t)NE * 4);
  ushort_t* psA  = (ushort_t*)carve((size_t)NN * FH * 2);  // ps1 bf16
  ushort_t* psB  = (ushort_t*)carve((size_t)NN * FH * 2);  // ps2 bf16
  ushort_t* bufB = (ushort_t*)carve((size_t)NN * FH * 2);  // h1 bf16
  ushort_t* bufD = (ushort_t*)carve((size_t)NN * FH * 2);  // r  bf16
  int*   root_i  = (int*)carve((size_t)NG * 4);
  int*   gcnt    = (int*)carve((size_t)NG * 4);
  float* rp      = (float*)carve((size_t)NG * FO * 4);

  k_init<<<64, 256, 0, stream>>>(pcnt, pcur, out);
  k_phist<<<256, 256, 0, stream>>>(ei, pcnt);
  k_pscan<<<1, 64, 0, stream>>>(pcnt, poff);
  k_pscatter<<<256, 256, 0, stream>>>(ei, poff, pcur, part_e);
  k_psort<<<NP, 1024, 0, stream>>>(part_e, poff, rowptr, dinv, csr_src);
  k_gemm1<<<NN / 16, 256, 0, stream>>>(x, W1, dinv, psA);
  k_root<<<1, 128, 0, stream>>>(bat, root_i, gcnt);
  k_rootproj<<<NG, 64, 0, stream>>>(x, W2, root_i, rp);
  k_agg<0><<<NN / 4, 256, 0, stream>>>(psA, dinv, rowptr, csr_src, b1, bufB);
  k_gemm2<<<NN / 16, 256, 0, stream>>>(bufB, W2, rp, bat, dinv, psB);
  k_agg<1><<<NN / 4, 256, 0, stream>>>(psB, dinv, rowptr, csr_src, b2, bufD);
  k_pool<<<(NN + 99) / 100, 64, 0, stream>>>(bufD, bat, out);
  k_final<<<(NG * FO + 255) / 256, 256, 0, stream>>>(out, gcnt, root_i, bufB);
}

// Round 9
// 332.516 us; speedup vs baseline: 1.3633x; 1.1095x over previous
//
#include <hip/hip_runtime.h>
#include <hip/hip_bf16.h>

#define NN 100000
#define NE 3200000
#define FIN 128
#define FH 64
#define FO 64
#define NG 128
#define NP 392       // partitions of 256 nodes (392*256 = 100352 >= NN)
#define PSH 8        // partition shift
#define PMASK 255
#define ECAP 9216    // static capacity per partition (expect 8192 +/- 90, 11 sigma margin)

typedef unsigned short ushort_t;

__device__ __forceinline__ float bf2f(ushort_t u) {
  unsigned v = ((unsigned)u) << 16;
  float f;
  __builtin_memcpy(&f, &v, 4);
  return f;
}
__device__ __forceinline__ ushort_t f2bf(float f) {
  __hip_bfloat16 b = __float2bfloat16(f);
  ushort_t u;
  __builtin_memcpy(&u, &b, 2);
  return u;
}

// ---------------- init: zero partition cursors + output; root binary search ----------------
__global__ void k_init(int* __restrict__ pcur, float* __restrict__ out,
                       const int* __restrict__ batch, int* __restrict__ root_idx,
                       int* __restrict__ gcnt) {
  int i = blockIdx.x * blockDim.x + threadIdx.x;
  if (i < NP) pcur[i] = 0;
  if (i < NG * (FO + FH)) out[i] = 0.0f;
  if (i < NG) {
    int g = i;
    int lo = 0, hi = NN;
    while (lo < hi) { int m = (lo + hi) >> 1; if (batch[m] < g) lo = m + 1; else hi = m; }
    int a = lo;
    lo = a; hi = NN;
    while (lo < hi) { int m = (lo + hi) >> 1; if (batch[m] < g + 1) lo = m + 1; else hi = m; }
    int b = lo;
    gcnt[g] = b - a;
    root_idx[g] = (b > a) ? a : (NN - 1);
  }
}

// ---------------- two-phase block-local scatter into static-capacity partitions ----------------
__global__ __launch_bounds__(256) void k_pscatter(const int* __restrict__ ei,
                                                  int* __restrict__ pcur,
                                                  int* __restrict__ part_e) {
  __shared__ int lbase[NP];
  __shared__ int lcur[NP];
  const int EPB = NE / 256;  // 12500
  int base = blockIdx.x * EPB;
  int tid = threadIdx.x;
  for (int i = tid; i < NP; i += 256) { lbase[i] = 0; lcur[i] = 0; }
  __syncthreads();
  for (int i = tid; i < EPB; i += 256) atomicAdd(&lbase[ei[NE + base + i] >> PSH], 1);
  __syncthreads();
  for (int i = tid; i < NP; i += 256) {
    int c = lbase[i];
    lbase[i] = c ? (i * ECAP + atomicAdd(&pcur[i], c)) : 0;
  }
  __syncthreads();
  for (int i = tid; i < EPB; i += 256) {
    int s = ei[base + i];
    int d = ei[NE + base + i];
    int p = d >> PSH;
    int pos = atomicAdd(&lcur[p], 1);
    part_e[lbase[p] + pos] = (s << PSH) | (d & PMASK);
  }
}

// ---------------- per-partition LDS counting sort -> CSR + rowptr/rend + dinv ----------------
__global__ __launch_bounds__(256) void k_psort(const int* __restrict__ part_e,
                                               const int* __restrict__ pcur,
                                               int* __restrict__ rowptr,
                                               int* __restrict__ rend,
                                               float* __restrict__ dinv,
                                               int* __restrict__ csr_src) {
  __shared__ int ew[ECAP];    // 36 KB
  __shared__ int cnt[256];
  __shared__ int pref[256];
  int p = blockIdx.x, tid = threadIdx.x;
  int pb = p * ECAP;
  int m = pcur[p];
  for (int i = tid; i < m; i += 256) ew[i] = part_e[pb + i];
  cnt[tid] = 0;
  __syncthreads();
  for (int i = tid; i < m; i += 256) atomicAdd(&cnt[ew[i] & PMASK], 1);
  __syncthreads();
  pref[tid] = cnt[tid];
  __syncthreads();
  for (int d = 1; d < 256; d <<= 1) {
    int t = (tid >= d) ? pref[tid - d] : 0;
    __syncthreads();
    pref[tid] += t;
    __syncthreads();
  }
  int excl = pref[tid] - cnt[tid];
  int n = (p << PSH) + tid;
  if (n < NN) {
    rowptr[n] = pb + excl;
    rend[n] = pb + excl + cnt[tid];
    dinv[n] = rsqrtf((float)cnt[tid] + 1.0f);
  }
  __syncthreads();
  pref[tid] = excl;
  __syncthreads();
  for (int i = tid; i < m; i += 256) {
    int w = ew[i];
    int pos = atomicAdd(&pref[w & PMASK], 1);
    csr_src[pb + pos] = w >> PSH;
  }
}

// ---------------- GEMM1: ps1 = bf16((x @ W1) * dinv[n]) ----------------
__global__ __launch_bounds__(256) void k_gemm1(const float* __restrict__ x,
                                               const float* __restrict__ W1,
                                               const float* __restrict__ dinv,
                                               ushort_t* __restrict__ ps) {
  __shared__ float Ws[FIN * FH];   // 32 KB
  __shared__ float Xs[16 * FIN];   // 8 KB
  int tid = threadIdx.x;
  for (int i = tid; i < FIN * FH; i += 256) Ws[i] = W1[i];
  long n0 = (long)blockIdx.x * 16;
  const float4* xg = (const float4*)(x + n0 * FIN);
  float4* xs4 = (float4*)Xs;
  for (int i = tid; i < 16 * FIN / 4; i += 256) xs4[i] = xg[i];
  __syncthreads();
  int f = tid & 63;
  int nl = tid >> 6;
  int b = nl * 4;
  float acc0 = 0.f, acc1 = 0.f, acc2 = 0.f, acc3 = 0.f;
  #pragma unroll 4
  for (int i = 0; i < FIN; i += 4) {
    float4 x0 = *(const float4*)&Xs[(b + 0) * FIN + i];
    float4 x1 = *(const float4*)&Xs[(b + 1) * FIN + i];
    float4 x2 = *(const float4*)&Xs[(b + 2) * FIN + i];
    float4 x3 = *(const float4*)&Xs[(b + 3) * FIN + i];
    float w0 = Ws[(i + 0) * FH + f];
    float w1 = Ws[(i + 1) * FH + f];
    float w2 = Ws[(i + 2) * FH + f];
    float w3 = Ws[(i + 3) * FH + f];
    acc0 += x0.x * w0 + x0.y * w1 + x0.z * w2 + x0.w * w3;
    acc1 += x1.x * w0 + x1.y * w1 + x1.z * w2 + x1.w * w3;
    acc2 += x2.x * w0 + x2.y * w1 + x2.z * w2 + x2.w * w3;
    acc3 += x3.x * w0 + x3.y * w1 + x3.z * w2 + x3.w * w3;
  }
  ps[(n0 + b + 0) * FH + f] = f2bf(acc0 * dinv[n0 + b + 0]);
  ps[(n0 + b + 1) * FH + f] = f2bf(acc1 * dinv[n0 + b + 1]);
  ps[(n0 + b + 2) * FH + f] = f2bf(acc2 * dinv[n0 + b + 2]);
  ps[(n0 + b + 3) * FH + f] = f2bf(acc3 * dinv[n0 + b + 3]);
}

// ---------------- per-graph root projection: relu(x[root]) @ W2[64:192,:] ----------------
__global__ __launch_bounds__(64) void k_rootproj(const float* __restrict__ x,
                                                 const float* __restrict__ W2,
                                                 const int* __restrict__ root_idx,
                                                 float* __restrict__ rp) {
  __shared__ float xr[FIN];
  int g = blockIdx.x;
  int t = threadIdx.x;
  long r = root_idx[g];
  xr[t]      = fmaxf(x[r * FIN + t], 0.0f);
  xr[t + 64] = fmaxf(x[r * FIN + t + 64], 0.0f);
  __syncthreads();
  float acc = 0.0f;
  #pragma unroll 8
  for (int i = 0; i < FIN; ++i) acc += xr[i] * W2[(FH + i) * FO + t];
  rp[g * FO + t] = acc;
}

// ---------------- per-node aggregation (wave per node, lane=feature, 16-deep MLP) ----------------
// ps prescaled by dinv[src]; out = bf16(dinv[n]*(ps[n]+sum ps[src]) + bias) [relu]
template <int RELU>
__global__ __launch_bounds__(256) void k_agg(const ushort_t* __restrict__ ps,
                                             const float* __restrict__ dinv,
                                             const int* __restrict__ rowptr,
                                             const int* __restrict__ rend,
                                             const int* __restrict__ csr_src,
                                             const float* __restrict__ bias,
                                             ushort_t* __restrict__ outb) {
  int wave = threadIdx.x >> 6;
  int lane = threadIdx.x & 63;
  int n = blockIdx.x * 4 + wave;   // grid exactly NN/4
  float acc = bf2f(ps[((long)n << 6) + lane]);  // self term (prescaled)
  int beg = rowptr[n], end = rend[n];
  int i = beg;
  for (; i + 16 <= end; i += 16) {
    int s0 = csr_src[i + 0];
    int s1 = csr_src[i + 1];
    int s2 = csr_src[i + 2];
    int s3 = csr_src[i + 3];
    int s4 = csr_src[i + 4];
    int s5 = csr_src[i + 5];
    int s6 = csr_src[i + 6];
    int s7 = csr_src[i + 7];
    int s8 = csr_src[i + 8];
    int s9 = csr_src[i + 9];
    int sa = csr_src[i + 10];
    int sb = csr_src[i + 11];
    int sc = csr_src[i + 12];
    int sd = csr_src[i + 13];
    int se = csr_src[i + 14];
    int sf = csr_src[i + 15];
    float v0 = bf2f(ps[((long)s0 << 6) + lane]);
    float v1 = bf2f(ps[((long)s1 << 6) + lane]);
    float v2 = bf2f(ps[((long)s2 << 6) + lane]);
    float v3 = bf2f(ps[((long)s3 << 6) + lane]);
    float v4 = bf2f(ps[((long)s4 << 6) + lane]);
    float v5 = bf2f(ps[((long)s5 << 6) + lane]);
    float v6 = bf2f(ps[((long)s6 << 6) + lane]);
    float v7 = bf2f(ps[((long)s7 << 6) + lane]);
    float v8 = bf2f(ps[((long)s8 << 6) + lane]);
    float v9 = bf2f(ps[((long)s9 << 6) + lane]);
    float va = bf2f(ps[((long)sa << 6) + lane]);
    float vb = bf2f(ps[((long)sb << 6) + lane]);
    float vc = bf2f(ps[((long)sc << 6) + lane]);
    float vd = bf2f(ps[((long)sd << 6) + lane]);
    float ve = bf2f(ps[((long)se << 6) + lane]);
    float vf = bf2f(ps[((long)sf << 6) + lane]);
    acc += v0; acc += v1; acc += v2; acc += v3;
    acc += v4; acc += v5; acc += v6; acc += v7;
    acc += v8; acc += v9; acc += va; acc += vb;
    acc += vc; acc += vd; acc += ve; acc += vf;
  }
  for (; i + 4 <= end; i += 4) {
    int s0 = csr_src[i + 0];
    int s1 = csr_src[i + 1];
    int s2 = csr_src[i + 2];
    int s3 = csr_src[i + 3];
    float v0 = bf2f(ps[((long)s0 << 6) + lane]);
    float v1 = bf2f(ps[((long)s1 << 6) + lane]);
    float v2 = bf2f(ps[((long)s2 << 6) + lane]);
    float v3 = bf2f(ps[((long)s3 << 6) + lane]);
    acc += v0; acc += v1; acc += v2; acc += v3;
  }
  for (; i < end; ++i) acc += bf2f(ps[((long)csr_src[i] << 6) + lane]);
  float val = dinv[n] * acc + bias[lane];
  if (RELU) val = fmaxf(val, 0.0f);
  outb[((long)n << 6) + lane] = f2bf(val);
}

// ---------------- GEMM2: ps2 = bf16((relu(h1) @ W2[0:64,:] + rp[batch]) * dinv) ----------------
__global__ __launch_bounds__(256) void k_gemm2(const ushort_t* __restrict__ h1,
                                               const float* __restrict__ W2,
                                               const float* __restrict__ rp,
                                               const int* __restrict__ batch,
                                               const float* __restrict__ dinv,
                                               ushort_t* __restrict__ ps2) {
  __shared__ float Ws[FH * FO];   // 16 KB
  __shared__ float Hs[16 * FH];   // 4 KB
  int tid = threadIdx.x;
  for (int i = tid; i < FH * FO; i += 256) Ws[i] = W2[i];
  long n0 = (long)blockIdx.x * 16;
  {
    ushort4 v = *(const ushort4*)(h1 + n0 * FH + tid * 4);
    float4 f;
    f.x = fmaxf(bf2f(v.x), 0.f); f.y = fmaxf(bf2f(v.y), 0.f);
    f.z = fmaxf(bf2f(v.z), 0.f); f.w = fmaxf(bf2f(v.w), 0.f);
    *(float4*)&Hs[tid * 4] = f;
  }
  __syncthreads();
  int f = tid & 63;
  int nl = tid >> 6;
  int b = nl * 4;
  float acc0 = rp[(long)batch[n0 + b + 0] * FO + f];
  float acc1 = rp[(long)batch[n0 + b + 1] * FO + f];
  float acc2 = rp[(long)batch[n0 + b + 2] * FO + f];
  float acc3 = rp[(long)batch[n0 + b + 3] * FO + f];
  #pragma unroll 4
  for (int j = 0; j < FH; j += 4) {
    float4 h0 = *(const float4*)&Hs[(b + 0) * FH + j];
    float4 h1v = *(const float4*)&Hs[(b + 1) * FH + j];
    float4 h2v = *(const float4*)&Hs[(b + 2) * FH + j];
    float4 h3 = *(const float4*)&Hs[(b + 3) * FH + j];
    float w0 = Ws[(j + 0) * FO + f];
    float w1 = Ws[(j + 1) * FO + f];
    float w2 = Ws[(j + 2) * FO + f];
    float w3 = Ws[(j + 3) * FO + f];
    acc0 += h0.x * w0 + h0.y * w1 + h0.z * w2 + h0.w * w3;
    acc1 += h1v.x * w0 + h1v.y * w1 + h1v.z * w2 + h1v.w * w3;
    acc2 += h2v.x * w0 + h2v.y * w1 + h2v.z * w2 + h2v.w * w3;
    acc3 += h3.x * w0 + h3.y * w1 + h3.z * w2 + h3.w * w3;
  }
  ps2[(n0 + b + 0) * FH + f] = f2bf(acc0 * dinv[n0 + b + 0]);
  ps2[(n0 + b + 1) * FH + f] = f2bf(acc1 * dinv[n0 + b + 1]);
  ps2[(n0 + b + 2) * FH + f] = f2bf(acc2 * dinv[n0 + b + 2]);
  ps2[(n0 + b + 3) * FH + f] = f2bf(acc3 * dinv[n0 + b + 3]);
}

// ---------------- mean-pool: segment sums of r (bf16) over batch ----------------
__global__ __launch_bounds__(64) void k_pool(const ushort_t* __restrict__ r,
                                             const int* __restrict__ batch,
                                             float* __restrict__ out) {
  const int PC = 100;
  int lane = threadIdx.x;
  long n0 = (long)blockIdx.x * PC;
  long n1 = n0 + PC;
  if (n1 > NN) n1 = NN;
  if (n0 >= NN) return;
  float acc = 0.0f;
  int cur = batch[n0];
  for (long n = n0; n < n1; ++n) {
    int g = batch[n];
    if (g != cur) {
      atomicAdd(&out[(long)cur * (FO + FH) + lane], acc);
      acc = 0.0f;
      cur = g;
    }
    acc += bf2f(r[n * FH + lane]);
  }
  atomicAdd(&out[(long)cur * (FO + FH) + lane], acc);
}

// ---------------- finalize: divide by count; fill root2 half ----------------
__global__ void k_final(float* __restrict__ out, const int* __restrict__ gcnt,
                        const int* __restrict__ root_idx, const ushort_t* __restrict__ h1full) {
  int i = blockIdx.x * blockDim.x + threadIdx.x;
  if (i >= NG * FO) return;
  int g = i >> 6, f = i & 63;
  int c = gcnt[g];
  float inv = 1.0f / fmaxf((float)c, 1.0f);
  out[g * (FO + FH) + f] *= inv;
  out[g * (FO + FH) + FO + f] = (c > 0) ? bf2f(h1full[(long)root_idx[g] * FH + f]) : 0.0f;
}

extern "C" void kernel_launch(void* const* d_in, const int* in_sizes, int n_in,
                              void* d_out, int out_size, void* d_ws, size_t ws_size,
                              hipStream_t stream) {
  const float* x   = (const float*)d_in[0];
  const int*   ei  = (const int*)d_in[1];
  const int*   bat = (const int*)d_in[2];
  const float* W1  = (const float*)d_in[3];
  const float* b1  = (const float*)d_in[4];
  const float* W2  = (const float*)d_in[5];
  const float* b2  = (const float*)d_in[6];
  float* out = (float*)d_out;

  char* p = (char*)d_ws;
  auto carve = [&](size_t bytes) -> void* {
    char* q = p;
    p += (bytes + 511) & ~size_t(511);
    return (void*)q;
  };
  float* dinv    = (float*)carve((size_t)NN * 4);
  int*   pcur    = (int*)carve((size_t)NP * 4);
  int*   part_e  = (int*)carve((size_t)NP * ECAP * 4);
  int*   rowptr  = (int*)carve((size_t)NN * 4);
  int*   rend    = (int*)carve((size_t)NN * 4);
  int*   csr_src = (int*)carve((size_t)NP * ECAP * 4);
  ushort_t* psA  = (ushort_t*)carve((size_t)NN * FH * 2);  // ps1 bf16
  ushort_t* psB  = (ushort_t*)carve((size_t)NN * FH * 2);  // ps2 bf16
  ushort_t* bufB = (ushort_t*)carve((size_t)NN * FH * 2);  // h1 bf16
  ushort_t* bufD = (ushort_t*)carve((size_t)NN * FH * 2);  // r  bf16
  int*   root_i  = (int*)carve((size_t)NG * 4);
  int*   gcnt    = (int*)carve((size_t)NG * 4);
  float* rp      = (float*)carve((size_t)NG * FO * 4);

  k_init<<<96, 256, 0, stream>>>(pcur, out, bat, root_i, gcnt);
  k_pscatter<<<256, 256, 0, stream>>>(ei, pcur, part_e);
  k_psort<<<NP, 256, 0, stream>>>(part_e, pcur, rowptr, rend, dinv, csr_src);
  k_gemm1<<<NN / 16, 256, 0, stream>>>(x, W1, dinv, psA);
  k_rootproj<<<NG, 64, 0, stream>>>(x, W2, root_i, rp);
  k_agg<0><<<NN / 4, 256, 0, stream>>>(psA, dinv, rowptr, rend, csr_src, b1, bufB);
  k_gemm2<<<NN / 16, 256, 0, stream>>>(bufB, W2, rp, bat, dinv, psB);
  k_agg<1><<<NN / 4, 256, 0, stream>>>(psB, dinv, rowptr, rend, csr_src, b2, bufD);
  k_pool<<<(NN + 99) / 100, 64, 0, stream>>>(bufD, bat, out);
  k_final<<<(NG * FO + 255) / 256, 256, 0, stream>>>(out, gcnt, root_i, bufB);
}

// Round 10
// 303.922 us; speedup vs baseline: 1.4915x; 1.0941x over previous
//
#include <hip/hip_runtime.h>
#include <hip/hip_bf16.h>

#define NN 100000
#define NE 3200000
#define FIN 128
#define FH 64
#define FO 64
#define NG 128
#define NP 392       // partitions of 256 nodes (392*256 = 100352 >= NN)
#define PSH 8        // partition shift
#define PMASK 255
#define ECAP 9216    // static capacity per partition (expect 8192 +/- 90, 11 sigma margin)

typedef unsigned short ushort_t;

__device__ __forceinline__ float bf2f(ushort_t u) {
  unsigned v = ((unsigned)u) << 16;
  float f;
  __builtin_memcpy(&f, &v, 4);
  return f;
}
__device__ __forceinline__ ushort_t f2bf(float f) {
  __hip_bfloat16 b = __float2bfloat16(f);
  ushort_t u;
  __builtin_memcpy(&u, &b, 2);
  return u;
}

// ---------------- init: zero partition cursors + output; root binary search ----------------
__global__ void k_init(int* __restrict__ pcur, float* __restrict__ out,
                       const int* __restrict__ batch, int* __restrict__ root_idx,
                       int* __restrict__ gcnt) {
  int i = blockIdx.x * blockDim.x + threadIdx.x;
  if (i < NP) pcur[i] = 0;
  if (i < NG * (FO + FH)) out[i] = 0.0f;
  if (i < NG) {
    int g = i;
    int lo = 0, hi = NN;
    while (lo < hi) { int m = (lo + hi) >> 1; if (batch[m] < g) lo = m + 1; else hi = m; }
    int a = lo;
    lo = a; hi = NN;
    while (lo < hi) { int m = (lo + hi) >> 1; if (batch[m] < g + 1) lo = m + 1; else hi = m; }
    int b = lo;
    gcnt[g] = b - a;
    root_idx[g] = (b > a) ? a : (NN - 1);
  }
}

// ---------------- two-phase block-local scatter into static-capacity partitions ----------------
__global__ __launch_bounds__(256) void k_pscatter(const int* __restrict__ ei,
                                                  int* __restrict__ pcur,
                                                  int* __restrict__ part_e) {
  __shared__ int lbase[NP];
  __shared__ int lcur[NP];
  const int EPB = NE / 256;  // 12500
  int base = blockIdx.x * EPB;
  int tid = threadIdx.x;
  for (int i = tid; i < NP; i += 256) { lbase[i] = 0; lcur[i] = 0; }
  __syncthreads();
  for (int i = tid; i < EPB; i += 256) atomicAdd(&lbase[ei[NE + base + i] >> PSH], 1);
  __syncthreads();
  for (int i = tid; i < NP; i += 256) {
    int c = lbase[i];
    lbase[i] = c ? (i * ECAP + atomicAdd(&pcur[i], c)) : 0;
  }
  __syncthreads();
  for (int i = tid; i < EPB; i += 256) {
    int s = ei[base + i];
    int d = ei[NE + base + i];
    int p = d >> PSH;
    int pos = atomicAdd(&lcur[p], 1);
    part_e[lbase[p] + pos] = (s << PSH) | (d & PMASK);
  }
}

// ---------------- per-partition LDS counting sort -> CSR + rowptr/rend + dinv ----------------
__global__ __launch_bounds__(256) void k_psort(const int* __restrict__ part_e,
                                               const int* __restrict__ pcur,
                                               int* __restrict__ rowptr,
                                               int* __restrict__ rend,
                                               float* __restrict__ dinv,
                                               int* __restrict__ csr_src) {
  __shared__ int ew[ECAP];    // 36 KB
  __shared__ int cnt[256];
  __shared__ int pref[256];
  int p = blockIdx.x, tid = threadIdx.x;
  int pb = p * ECAP;
  int m = pcur[p];
  for (int i = tid; i < m; i += 256) ew[i] = part_e[pb + i];
  cnt[tid] = 0;
  __syncthreads();
  for (int i = tid; i < m; i += 256) atomicAdd(&cnt[ew[i] & PMASK], 1);
  __syncthreads();
  pref[tid] = cnt[tid];
  __syncthreads();
  for (int d = 1; d < 256; d <<= 1) {
    int t = (tid >= d) ? pref[tid - d] : 0;
    __syncthreads();
    pref[tid] += t;
    __syncthreads();
  }
  int excl = pref[tid] - cnt[tid];
  int n = (p << PSH) + tid;
  if (n < NN) {
    rowptr[n] = pb + excl;
    rend[n] = pb + excl + cnt[tid];
    dinv[n] = rsqrtf((float)cnt[tid] + 1.0f);
  }
  __syncthreads();
  pref[tid] = excl;
  __syncthreads();
  for (int i = tid; i < m; i += 256) {
    int w = ew[i];
    int pos = atomicAdd(&pref[w & PMASK], 1);
    csr_src[pb + pos] = w >> PSH;
  }
}

// ---------------- GEMM1: ps1 = bf16((x @ W1) * dinv[n]) ----------------
__global__ __launch_bounds__(256) void k_gemm1(const float* __restrict__ x,
                                               const float* __restrict__ W1,
                                               const float* __restrict__ dinv,
                                               ushort_t* __restrict__ ps) {
  __shared__ float Ws[FIN * FH];   // 32 KB
  __shared__ float Xs[16 * FIN];   // 8 KB
  int tid = threadIdx.x;
  for (int i = tid; i < FIN * FH; i += 256) Ws[i] = W1[i];
  long n0 = (long)blockIdx.x * 16;
  const float4* xg = (const float4*)(x + n0 * FIN);
  float4* xs4 = (float4*)Xs;
  for (int i = tid; i < 16 * FIN / 4; i += 256) xs4[i] = xg[i];
  __syncthreads();
  int f = tid & 63;
  int nl = tid >> 6;
  int b = nl * 4;
  float acc0 = 0.f, acc1 = 0.f, acc2 = 0.f, acc3 = 0.f;
  #pragma unroll 4
  for (int i = 0; i < FIN; i += 4) {
    float4 x0 = *(const float4*)&Xs[(b + 0) * FIN + i];
    float4 x1 = *(const float4*)&Xs[(b + 1) * FIN + i];
    float4 x2 = *(const float4*)&Xs[(b + 2) * FIN + i];
    float4 x3 = *(const float4*)&Xs[(b + 3) * FIN + i];
    float w0 = Ws[(i + 0) * FH + f];
    float w1 = Ws[(i + 1) * FH + f];
    float w2 = Ws[(i + 2) * FH + f];
    float w3 = Ws[(i + 3) * FH + f];
    acc0 += x0.x * w0 + x0.y * w1 + x0.z * w2 + x0.w * w3;
    acc1 += x1.x * w0 + x1.y * w1 + x1.z * w2 + x1.w * w3;
    acc2 += x2.x * w0 + x2.y * w1 + x2.z * w2 + x2.w * w3;
    acc3 += x3.x * w0 + x3.y * w1 + x3.z * w2 + x3.w * w3;
  }
  ps[(n0 + b + 0) * FH + f] = f2bf(acc0 * dinv[n0 + b + 0]);
  ps[(n0 + b + 1) * FH + f] = f2bf(acc1 * dinv[n0 + b + 1]);
  ps[(n0 + b + 2) * FH + f] = f2bf(acc2 * dinv[n0 + b + 2]);
  ps[(n0 + b + 3) * FH + f] = f2bf(acc3 * dinv[n0 + b + 3]);
}

// ---------------- per-graph root projection: relu(x[root]) @ W2[64:192,:] ----------------
__global__ __launch_bounds__(64) void k_rootproj(const float* __restrict__ x,
                                                 const float* __restrict__ W2,
                                                 const int* __restrict__ root_idx,
                                                 float* __restrict__ rp) {
  __shared__ float xr[FIN];
  int g = blockIdx.x;
  int t = threadIdx.x;
  long r = root_idx[g];
  xr[t]      = fmaxf(x[r * FIN + t], 0.0f);
  xr[t + 64] = fmaxf(x[r * FIN + t + 64], 0.0f);
  __syncthreads();
  float acc = 0.0f;
  #pragma unroll 8
  for (int i = 0; i < FIN; ++i) acc += xr[i] * W2[(FH + i) * FO + t];
  rp[g * FO + t] = acc;
}

// ---------------- per-node aggregation (wave per node, scalarized addressing) ----------------
// ps prescaled by dinv[src]; out = bf16(dinv[n]*(ps[n]+sum ps[src]) + bias) [relu]
// n/beg/end/src forced into SGPRs via readfirstlane -> gather address math on SALU,
// leaving only 2 VALU/edge (bf16 shift + add). 16 gathers in flight.
template <int RELU>
__global__ __launch_bounds__(256) void k_agg(const ushort_t* __restrict__ ps,
                                             const float* __restrict__ dinv,
                                             const int* __restrict__ rowptr,
                                             const int* __restrict__ rend,
                                             const int* __restrict__ csr_src,
                                             const float* __restrict__ bias,
                                             ushort_t* __restrict__ outb) {
  int lane = threadIdx.x & 63;
  int n = __builtin_amdgcn_readfirstlane(blockIdx.x * 4 + (threadIdx.x >> 6));
  int beg = __builtin_amdgcn_readfirstlane(rowptr[n]);
  int end = __builtin_amdgcn_readfirstlane(rend[n]);
  float acc = bf2f(ps[((long)n << 6) + lane]);  // self term (prescaled)
  int i = beg;
  for (; i + 16 <= end; i += 16) {
    int s0 = __builtin_amdgcn_readfirstlane(csr_src[i + 0]);
    int s1 = __builtin_amdgcn_readfirstlane(csr_src[i + 1]);
    int s2 = __builtin_amdgcn_readfirstlane(csr_src[i + 2]);
    int s3 = __builtin_amdgcn_readfirstlane(csr_src[i + 3]);
    int s4 = __builtin_amdgcn_readfirstlane(csr_src[i + 4]);
    int s5 = __builtin_amdgcn_readfirstlane(csr_src[i + 5]);
    int s6 = __builtin_amdgcn_readfirstlane(csr_src[i + 6]);
    int s7 = __builtin_amdgcn_readfirstlane(csr_src[i + 7]);
    int s8 = __builtin_amdgcn_readfirstlane(csr_src[i + 8]);
    int s9 = __builtin_amdgcn_readfirstlane(csr_src[i + 9]);
    int sa = __builtin_amdgcn_readfirstlane(csr_src[i + 10]);
    int sb = __builtin_amdgcn_readfirstlane(csr_src[i + 11]);
    int sc = __builtin_amdgcn_readfirstlane(csr_src[i + 12]);
    int sd = __builtin_amdgcn_readfirstlane(csr_src[i + 13]);
    int se = __builtin_amdgcn_readfirstlane(csr_src[i + 14]);
    int sf = __builtin_amdgcn_readfirstlane(csr_src[i + 15]);
    float v0 = bf2f(ps[((long)s0 << 6) + lane]);
    float v1 = bf2f(ps[((long)s1 << 6) + lane]);
    float v2 = bf2f(ps[((long)s2 << 6) + lane]);
    float v3 = bf2f(ps[((long)s3 << 6) + lane]);
    float v4 = bf2f(ps[((long)s4 << 6) + lane]);
    float v5 = bf2f(ps[((long)s5 << 6) + lane]);
    float v6 = bf2f(ps[((long)s6 << 6) + lane]);
    float v7 = bf2f(ps[((long)s7 << 6) + lane]);
    float v8 = bf2f(ps[((long)s8 << 6) + lane]);
    float v9 = bf2f(ps[((long)s9 << 6) + lane]);
    float va = bf2f(ps[((long)sa << 6) + lane]);
    float vb = bf2f(ps[((long)sb << 6) + lane]);
    float vc = bf2f(ps[((long)sc << 6) + lane]);
    float vd = bf2f(ps[((long)sd << 6) + lane]);
    float ve = bf2f(ps[((long)se << 6) + lane]);
    float vf = bf2f(ps[((long)sf << 6) + lane]);
    acc += v0; acc += v1; acc += v2; acc += v3;
    acc += v4; acc += v5; acc += v6; acc += v7;
    acc += v8; acc += v9; acc += va; acc += vb;
    acc += vc; acc += vd; acc += ve; acc += vf;
  }
  for (; i + 4 <= end; i += 4) {
    int s0 = __builtin_amdgcn_readfirstlane(csr_src[i + 0]);
    int s1 = __builtin_amdgcn_readfirstlane(csr_src[i + 1]);
    int s2 = __builtin_amdgcn_readfirstlane(csr_src[i + 2]);
    int s3 = __builtin_amdgcn_readfirstlane(csr_src[i + 3]);
    float v0 = bf2f(ps[((long)s0 << 6) + lane]);
    float v1 = bf2f(ps[((long)s1 << 6) + lane]);
    float v2 = bf2f(ps[((long)s2 << 6) + lane]);
    float v3 = bf2f(ps[((long)s3 << 6) + lane]);
    acc += v0; acc += v1; acc += v2; acc += v3;
  }
  for (; i < end; ++i) {
    int s = __builtin_amdgcn_readfirstlane(csr_src[i]);
    acc += bf2f(ps[((long)s << 6) + lane]);
  }
  float val = dinv[n] * acc + bias[lane];
  if (RELU) val = fmaxf(val, 0.0f);
  outb[((long)n << 6) + lane] = f2bf(val);
}

// ---------------- GEMM2: ps2 = bf16((relu(h1) @ W2[0:64,:] + rp[batch]) * dinv) ----------------
__global__ __launch_bounds__(256) void k_gemm2(const ushort_t* __restrict__ h1,
                                               const float* __restrict__ W2,
                                               const float* __restrict__ rp,
                                               const int* __restrict__ batch,
                                               const float* __restrict__ dinv,
                                               ushort_t* __restrict__ ps2) {
  __shared__ float Ws[FH * FO];   // 16 KB
  __shared__ float Hs[16 * FH];   // 4 KB
  int tid = threadIdx.x;
  for (int i = tid; i < FH * FO; i += 256) Ws[i] = W2[i];
  long n0 = (long)blockIdx.x * 16;
  {
    ushort4 v = *(const ushort4*)(h1 + n0 * FH + tid * 4);
    float4 f;
    f.x = fmaxf(bf2f(v.x), 0.f); f.y = fmaxf(bf2f(v.y), 0.f);
    f.z = fmaxf(bf2f(v.z), 0.f); f.w = fmaxf(bf2f(v.w), 0.f);
    *(float4*)&Hs[tid * 4] = f;
  }
  __syncthreads();
  int f = tid & 63;
  int nl = tid >> 6;
  int b = nl * 4;
  float acc0 = rp[(long)batch[n0 + b + 0] * FO + f];
  float acc1 = rp[(long)batch[n0 + b + 1] * FO + f];
  float acc2 = rp[(long)batch[n0 + b + 2] * FO + f];
  float acc3 = rp[(long)batch[n0 + b + 3] * FO + f];
  #pragma unroll 4
  for (int j = 0; j < FH; j += 4) {
    float4 h0 = *(const float4*)&Hs[(b + 0) * FH + j];
    float4 h1v = *(const float4*)&Hs[(b + 1) * FH + j];
    float4 h2v = *(const float4*)&Hs[(b + 2) * FH + j];
    float4 h3 = *(const float4*)&Hs[(b + 3) * FH + j];
    float w0 = Ws[(j + 0) * FO + f];
    float w1 = Ws[(j + 1) * FO + f];
    float w2 = Ws[(j + 2) * FO + f];
    float w3 = Ws[(j + 3) * FO + f];
    acc0 += h0.x * w0 + h0.y * w1 + h0.z * w2 + h0.w * w3;
    acc1 += h1v.x * w0 + h1v.y * w1 + h1v.z * w2 + h1v.w * w3;
    acc2 += h2v.x * w0 + h2v.y * w1 + h2v.z * w2 + h2v.w * w3;
    acc3 += h3.x * w0 + h3.y * w1 + h3.z * w2 + h3.w * w3;
  }
  ps2[(n0 + b + 0) * FH + f] = f2bf(acc0 * dinv[n0 + b + 0]);
  ps2[(n0 + b + 1) * FH + f] = f2bf(acc1 * dinv[n0 + b + 1]);
  ps2[(n0 + b + 2) * FH + f] = f2bf(acc2 * dinv[n0 + b + 2]);
  ps2[(n0 + b + 3) * FH + f] = f2bf(acc3 * dinv[n0 + b + 3]);
}

// ---------------- mean-pool: segment sums of r (bf16) over batch ----------------
__global__ __launch_bounds__(64) void k_pool(const ushort_t* __restrict__ r,
                                             const int* __restrict__ batch,
                                             float* __restrict__ out) {
  const int PC = 100;
  int lane = threadIdx.x;
  long n0 = (long)blockIdx.x * PC;
  long n1 = n0 + PC;
  if (n1 > NN) n1 = NN;
  if (n0 >= NN) return;
  float acc = 0.0f;
  int cur = batch[n0];
  for (long n = n0; n < n1; ++n) {
    int g = batch[n];
    if (g != cur) {
      atomicAdd(&out[(long)cur * (FO + FH) + lane], acc);
      acc = 0.0f;
      cur = g;
    }
    acc += bf2f(r[n * FH + lane]);
  }
  atomicAdd(&out[(long)cur * (FO + FH) + lane], acc);
}

// ---------------- finalize: divide by count; fill root2 half ----------------
__global__ void k_final(float* __restrict__ out, const int* __restrict__ gcnt,
                        const int* __restrict__ root_idx, const ushort_t* __restrict__ h1full) {
  int i = blockIdx.x * blockDim.x + threadIdx.x;
  if (i >= NG * FO) return;
  int g = i >> 6, f = i & 63;
  int c = gcnt[g];
  float inv = 1.0f / fmaxf((float)c, 1.0f);
  out[g * (FO + FH) + f] *= inv;
  out[g * (FO + FH) + FO + f] = (c > 0) ? bf2f(h1full[(long)root_idx[g] * FH + f]) : 0.0f;
}

extern "C" void kernel_launch(void* const* d_in, const int* in_sizes, int n_in,
                              void* d_out, int out_size, void* d_ws, size_t ws_size,
                              hipStream_t stream) {
  const float* x   = (const float*)d_in[0];
  const int*   ei  = (const int*)d_in[1];
  const int*   bat = (const int*)d_in[2];
  const float* W1  = (const float*)d_in[3];
  const float* b1  = (const float*)d_in[4];
  const float* W2  = (const float*)d_in[5];
  const float* b2  = (const float*)d_in[6];
  float* out = (float*)d_out;

  char* p = (char*)d_ws;
  auto carve = [&](size_t bytes) -> void* {
    char* q = p;
    p += (bytes + 511) & ~size_t(511);
    return (void*)q;
  };
  float* dinv    = (float*)carve((size_t)NN * 4);
  int*   pcur    = (int*)carve((size_t)NP * 4);
  int*   part_e  = (int*)carve((size_t)NP * ECAP * 4);
  int*   rowptr  = (int*)carve((size_t)NN * 4);
  int*   rend    = (int*)carve((size_t)NN * 4);
  int*   csr_src = (int*)carve((size_t)NP * ECAP * 4);
  ushort_t* psA  = (ushort_t*)carve((size_t)NN * FH * 2);  // ps1 bf16
  ushort_t* psB  = (ushort_t*)carve((size_t)NN * FH * 2);  // ps2 bf16
  ushort_t* bufB = (ushort_t*)carve((size_t)NN * FH * 2);  // h1 bf16
  ushort_t* bufD = (ushort_t*)carve((size_t)NN * FH * 2);  // r  bf16
  int*   root_i  = (int*)carve((size_t)NG * 4);
  int*   gcnt    = (int*)carve((size_t)NG * 4);
  float* rp      = (float*)carve((size_t)NG * FO * 4);

  k_init<<<96, 256, 0, stream>>>(pcur, out, bat, root_i, gcnt);
  k_pscatter<<<256, 256, 0, stream>>>(ei, pcur, part_e);
  k_psort<<<NP, 256, 0, stream>>>(part_e, pcur, rowptr, rend, dinv, csr_src);
  k_gemm1<<<NN / 16, 256, 0, stream>>>(x, W1, dinv, psA);
  k_rootproj<<<NG, 64, 0, stream>>>(x, W2, root_i, rp);
  k_agg<0><<<NN / 4, 256, 0, stream>>>(psA, dinv, rowptr, rend, csr_src, b1, bufB);
  k_gemm2<<<NN / 16, 256, 0, stream>>>(bufB, W2, rp, bat, dinv, psB);
  k_agg<1><<<NN / 4, 256, 0, stream>>>(psB, dinv, rowptr, rend, csr_src, b2, bufD);
  k_pool<<<(NN + 99) / 100, 64, 0, stream>>>(bufD, bat, out);
  k_final<<<(NG * FO + 255) / 256, 256, 0, stream>>>(out, gcnt, root_i, bufB);
}

// Round 11
// 276.261 us; speedup vs baseline: 1.6409x; 1.1001x over previous
//
#include <hip/hip_runtime.h>
#include <hip/hip_bf16.h>

#define NN 100000
#define NE 3200000
#define FIN 128
#define FH 64
#define FO 64
#define NG 128
#define NP 392       // partitions of 256 nodes
#define PSH 8
#define PMASK 255
#define ECAP 9216    // static capacity per partition (expect 8192 +/- 90)
#define XP 132       // padded Xs row (floats): 4-row group stride 528 words -> 2-way (free)
#define HP 68        // padded Hs row

typedef unsigned short ushort_t;

__device__ __forceinline__ float bf2f(ushort_t u) {
  unsigned v = ((unsigned)u) << 16;
  float f;
  __builtin_memcpy(&f, &v, 4);
  return f;
}
__device__ __forceinline__ ushort_t f2bf(float f) {
  __hip_bfloat16 b = __float2bfloat16(f);
  ushort_t u;
  __builtin_memcpy(&u, &b, 2);
  return u;
}

#define FMA4(a, xv, w0, w1, w2, w3)                          \
  a.x += xv.x * w0.x + xv.y * w1.x + xv.z * w2.x + xv.w * w3.x; \
  a.y += xv.x * w0.y + xv.y * w1.y + xv.z * w2.y + xv.w * w3.y; \
  a.z += xv.x * w0.z + xv.y * w1.z + xv.z * w2.z + xv.w * w3.z; \
  a.w += xv.x * w0.w + xv.y * w1.w + xv.z * w2.w + xv.w * w3.w;

// ---------------- init + root binary search ----------------
__global__ void k_init(int* __restrict__ pcur, float* __restrict__ out,
                       const int* __restrict__ batch, int* __restrict__ root_idx,
                       int* __restrict__ gcnt) {
  int i = blockIdx.x * blockDim.x + threadIdx.x;
  if (i < NP) pcur[i] = 0;
  if (i < NG * (FO + FH)) out[i] = 0.0f;
  if (i < NG) {
    int g = i;
    int lo = 0, hi = NN;
    while (lo < hi) { int m = (lo + hi) >> 1; if (batch[m] < g) lo = m + 1; else hi = m; }
    int a = lo;
    lo = a; hi = NN;
    while (lo < hi) { int m = (lo + hi) >> 1; if (batch[m] < g + 1) lo = m + 1; else hi = m; }
    int b = lo;
    gcnt[g] = b - a;
    root_idx[g] = (b > a) ? a : (NN - 1);
  }
}

// ---------------- two-phase block-local scatter (1024 thr: 16 waves/CU) ----------------
__global__ __launch_bounds__(1024) void k_pscatter(const int* __restrict__ ei,
                                                   int* __restrict__ pcur,
                                                   int* __restrict__ part_e) {
  __shared__ int lbase[NP];
  __shared__ int lcur[NP];
  const int EPB = NE / 256;  // 12500
  int base = blockIdx.x * EPB;
  int tid = threadIdx.x;
  for (int i = tid; i < NP; i += 1024) { lbase[i] = 0; lcur[i] = 0; }
  __syncthreads();
  for (int i = tid; i < EPB; i += 1024) atomicAdd(&lbase[ei[NE + base + i] >> PSH], 1);
  __syncthreads();
  for (int i = tid; i < NP; i += 1024) {
    int c = lbase[i];
    lbase[i] = c ? (i * ECAP + atomicAdd(&pcur[i], c)) : 0;
  }
  __syncthreads();
  for (int i = tid; i < EPB; i += 1024) {
    int s = ei[base + i];
    int d = ei[NE + base + i];
    int p = d >> PSH;
    int pos = atomicAdd(&lcur[p], 1);
    part_e[lbase[p] + pos] = (s << PSH) | (d & PMASK);
  }
}

// ---------------- per-partition LDS counting sort ----------------
__global__ __launch_bounds__(256) void k_psort(const int* __restrict__ part_e,
                                               const int* __restrict__ pcur,
                                               int* __restrict__ rowptr,
                                               int* __restrict__ rend,
                                               float* __restrict__ dinv,
                                               int* __restrict__ csr_src) {
  __shared__ int ew[ECAP];    // 36 KB
  __shared__ int cnt[256];
  __shared__ int pref[256];
  int p = blockIdx.x, tid = threadIdx.x;
  int pb = p * ECAP;
  int m = pcur[p];
  for (int i = tid; i < m; i += 256) ew[i] = part_e[pb + i];
  cnt[tid] = 0;
  __syncthreads();
  for (int i = tid; i < m; i += 256) atomicAdd(&cnt[ew[i] & PMASK], 1);
  __syncthreads();
  pref[tid] = cnt[tid];
  __syncthreads();
  for (int d = 1; d < 256; d <<= 1) {
    int t = (tid >= d) ? pref[tid - d] : 0;
    __syncthreads();
    pref[tid] += t;
    __syncthreads();
  }
  int excl = pref[tid] - cnt[tid];
  int n = (p << PSH) + tid;
  if (n < NN) {
    rowptr[n] = pb + excl;
    rend[n] = pb + excl + cnt[tid];
    dinv[n] = rsqrtf((float)cnt[tid] + 1.0f);
  }
  __syncthreads();
  pref[tid] = excl;
  __syncthreads();
  for (int i = tid; i < m; i += 256) {
    int w = ew[i];
    int pos = atomicAdd(&pref[w & PMASK], 1);
    csr_src[pb + pos] = w >> PSH;
  }
}

// ---------------- GEMM1: ps1 = bf16((x @ W1) * dinv) ; 64-node tile, 4x4/thread ----------------
__global__ __launch_bounds__(256) void k_gemm1(const float* __restrict__ x,
                                               const float* __restrict__ W1,
                                               const float* __restrict__ dinv,
                                               ushort_t* __restrict__ ps) {
  __shared__ float Xs[64 * XP];    // 33 KB
  __shared__ float Ws[FIN * FH];   // 32 KB
  int tid = threadIdx.x;
  long n0 = (long)blockIdx.x * 64;
  int nvalid = (int)(NN - n0);  // may exceed 64
  { // stage W1 (128x64)
    const float4* wg = (const float4*)W1;
    float4* ws4 = (float4*)Ws;
    for (int i = tid; i < FIN * FH / 4; i += 256) ws4[i] = wg[i];
  }
  { // stage Xs rows (guarded), pad XP
    const float4* xg = (const float4*)(x + n0 * FIN);
    for (int i = tid; i < 64 * 32; i += 256) {
      int r = i >> 5, c = i & 31;
      if (r < nvalid) *(float4*)&Xs[r * XP + c * 4] = xg[(long)r * 32 + c];
    }
  }
  __syncthreads();
  int fg = tid & 15, ng = tid >> 4;
  int f0 = fg * 4, b = ng * 4;
  float4 a0 = {0, 0, 0, 0}, a1 = a0, a2 = a0, a3 = a0;
  #pragma unroll 8
  for (int k = 0; k < FIN; k += 4) {
    float4 x0 = *(const float4*)&Xs[(b + 0) * XP + k];
    float4 x1 = *(const float4*)&Xs[(b + 1) * XP + k];
    float4 x2 = *(const float4*)&Xs[(b + 2) * XP + k];
    float4 x3 = *(const float4*)&Xs[(b + 3) * XP + k];
    float4 w0 = *(const float4*)&Ws[(k + 0) * FH + f0];
    float4 w1 = *(const float4*)&Ws[(k + 1) * FH + f0];
    float4 w2 = *(const float4*)&Ws[(k + 2) * FH + f0];
    float4 w3 = *(const float4*)&Ws[(k + 3) * FH + f0];
    FMA4(a0, x0, w0, w1, w2, w3);
    FMA4(a1, x1, w0, w1, w2, w3);
    FMA4(a2, x2, w0, w1, w2, w3);
    FMA4(a3, x3, w0, w1, w2, w3);
  }
  #pragma unroll
  for (int i = 0; i < 4; ++i) {
    if (b + i < nvalid) {
      float4 a = (i == 0) ? a0 : (i == 1) ? a1 : (i == 2) ? a2 : a3;
      float dn = dinv[n0 + b + i];
      ushort4 o;
      o.x = f2bf(a.x * dn); o.y = f2bf(a.y * dn);
      o.z = f2bf(a.z * dn); o.w = f2bf(a.w * dn);
      *(ushort4*)(ps + (n0 + b + i) * FH + f0) = o;
    }
  }
}

// ---------------- per-graph root projection ----------------
__global__ __launch_bounds__(64) void k_rootproj(const float* __restrict__ x,
                                                 const float* __restrict__ W2,
                                                 const int* __restrict__ root_idx,
                                                 float* __restrict__ rp) {
  __shared__ float xr[FIN];
  int g = blockIdx.x;
  int t = threadIdx.x;
  long r = root_idx[g];
  xr[t]      = fmaxf(x[r * FIN + t], 0.0f);
  xr[t + 64] = fmaxf(x[r * FIN + t + 64], 0.0f);
  __syncthreads();
  float acc = 0.0f;
  #pragma unroll 8
  for (int i = 0; i < FIN; ++i) acc += xr[i] * W2[(FH + i) * FO + t];
  rp[g * FO + t] = acc;
}

// ---------------- per-node aggregation (scalarized, 16-deep MLP) ----------------
template <int RELU>
__global__ __launch_bounds__(256) void k_agg(const ushort_t* __restrict__ ps,
                                             const float* __restrict__ dinv,
                                             const int* __restrict__ rowptr,
                                             const int* __restrict__ rend,
                                             const int* __restrict__ csr_src,
                                             const float* __restrict__ bias,
                                             ushort_t* __restrict__ outb) {
  int lane = threadIdx.x & 63;
  int n = __builtin_amdgcn_readfirstlane(blockIdx.x * 4 + (threadIdx.x >> 6));
  int beg = __builtin_amdgcn_readfirstlane(rowptr[n]);
  int end = __builtin_amdgcn_readfirstlane(rend[n]);
  float acc = bf2f(ps[((long)n << 6) + lane]);
  int i = beg;
  for (; i + 16 <= end; i += 16) {
    int s0 = __builtin_amdgcn_readfirstlane(csr_src[i + 0]);
    int s1 = __builtin_amdgcn_readfirstlane(csr_src[i + 1]);
    int s2 = __builtin_amdgcn_readfirstlane(csr_src[i + 2]);
    int s3 = __builtin_amdgcn_readfirstlane(csr_src[i + 3]);
    int s4 = __builtin_amdgcn_readfirstlane(csr_src[i + 4]);
    int s5 = __builtin_amdgcn_readfirstlane(csr_src[i + 5]);
    int s6 = __builtin_amdgcn_readfirstlane(csr_src[i + 6]);
    int s7 = __builtin_amdgcn_readfirstlane(csr_src[i + 7]);
    int s8 = __builtin_amdgcn_readfirstlane(csr_src[i + 8]);
    int s9 = __builtin_amdgcn_readfirstlane(csr_src[i + 9]);
    int sa = __builtin_amdgcn_readfirstlane(csr_src[i + 10]);
    int sb = __builtin_amdgcn_readfirstlane(csr_src[i + 11]);
    int sc = __builtin_amdgcn_readfirstlane(csr_src[i + 12]);
    int sd = __builtin_amdgcn_readfirstlane(csr_src[i + 13]);
    int se = __builtin_amdgcn_readfirstlane(csr_src[i + 14]);
    int sf = __builtin_amdgcn_readfirstlane(csr_src[i + 15]);
    float v0 = bf2f(ps[((long)s0 << 6) + lane]);
    float v1 = bf2f(ps[((long)s1 << 6) + lane]);
    float v2 = bf2f(ps[((long)s2 << 6) + lane]);
    float v3 = bf2f(ps[((long)s3 << 6) + lane]);
    float v4 = bf2f(ps[((long)s4 << 6) + lane]);
    float v5 = bf2f(ps[((long)s5 << 6) + lane]);
    float v6 = bf2f(ps[((long)s6 << 6) + lane]);
    float v7 = bf2f(ps[((long)s7 << 6) + lane]);
    float v8 = bf2f(ps[((long)s8 << 6) + lane]);
    float v9 = bf2f(ps[((long)s9 << 6) + lane]);
    float va = bf2f(ps[((long)sa << 6) + lane]);
    float vb = bf2f(ps[((long)sb << 6) + lane]);
    float vc = bf2f(ps[((long)sc << 6) + lane]);
    float vd = bf2f(ps[((long)sd << 6) + lane]);
    float ve = bf2f(ps[((long)se << 6) + lane]);
    float vf = bf2f(ps[((long)sf << 6) + lane]);
    acc += v0; acc += v1; acc += v2; acc += v3;
    acc += v4; acc += v5; acc += v6; acc += v7;
    acc += v8; acc += v9; acc += va; acc += vb;
    acc += vc; acc += vd; acc += ve; acc += vf;
  }
  for (; i + 4 <= end; i += 4) {
    int s0 = __builtin_amdgcn_readfirstlane(csr_src[i + 0]);
    int s1 = __builtin_amdgcn_readfirstlane(csr_src[i + 1]);
    int s2 = __builtin_amdgcn_readfirstlane(csr_src[i + 2]);
    int s3 = __builtin_amdgcn_readfirstlane(csr_src[i + 3]);
    float v0 = bf2f(ps[((long)s0 << 6) + lane]);
    float v1 = bf2f(ps[((long)s1 << 6) + lane]);
    float v2 = bf2f(ps[((long)s2 << 6) + lane]);
    float v3 = bf2f(ps[((long)s3 << 6) + lane]);
    acc += v0; acc += v1; acc += v2; acc += v3;
  }
  for (; i < end; ++i) {
    int s = __builtin_amdgcn_readfirstlane(csr_src[i]);
    acc += bf2f(ps[((long)s << 6) + lane]);
  }
  float val = dinv[n] * acc + bias[lane];
  if (RELU) val = fmaxf(val, 0.0f);
  outb[((long)n << 6) + lane] = f2bf(val);
}

// ---------------- GEMM2: 64-node tile, 4x4/thread ----------------
__global__ __launch_bounds__(256) void k_gemm2(const ushort_t* __restrict__ h1,
                                               const float* __restrict__ W2,
                                               const float* __restrict__ rp,
                                               const int* __restrict__ batch,
                                               const float* __restrict__ dinv,
                                               ushort_t* __restrict__ ps2) {
  __shared__ float Hs[64 * HP];    // 17 KB
  __shared__ float Ws[FH * FO];    // 16 KB
  int tid = threadIdx.x;
  long n0 = (long)blockIdx.x * 64;
  int nvalid = (int)(NN - n0);
  { // stage W2 rows 0..63
    const float4* wg = (const float4*)W2;
    float4* ws4 = (float4*)Ws;
    for (int i = tid; i < FH * FO / 4; i += 256) ws4[i] = wg[i];
  }
  { // stage relu(bf16 h1) -> fp32, pad HP
    for (int i = tid; i < 64 * 16; i += 256) {
      int r = i >> 4, c = i & 15;
      if (r < nvalid) {
        ushort4 v = *(const ushort4*)(h1 + (n0 + r) * FH + c * 4);
        float4 f;
        f.x = fmaxf(bf2f(v.x), 0.f); f.y = fmaxf(bf2f(v.y), 0.f);
        f.z = fmaxf(bf2f(v.z), 0.f); f.w = fmaxf(bf2f(v.w), 0.f);
        *(float4*)&Hs[r * HP + c * 4] = f;
      }
    }
  }
  __syncthreads();
  int fg = tid & 15, ng = tid >> 4;
  int f0 = fg * 4, b = ng * 4;
  float4 a0 = {0, 0, 0, 0}, a1 = a0, a2 = a0, a3 = a0;
  #pragma unroll 8
  for (int k = 0; k < FH; k += 4) {
    float4 x0 = *(const float4*)&Hs[(b + 0) * HP + k];
    float4 x1 = *(const float4*)&Hs[(b + 1) * HP + k];
    float4 x2 = *(const float4*)&Hs[(b + 2) * HP + k];
    float4 x3 = *(const float4*)&Hs[(b + 3) * HP + k];
    float4 w0 = *(const float4*)&Ws[(k + 0) * FO + f0];
    float4 w1 = *(const float4*)&Ws[(k + 1) * FO + f0];
    float4 w2 = *(const float4*)&Ws[(k + 2) * FO + f0];
    float4 w3 = *(const float4*)&Ws[(k + 3) * FO + f0];
    FMA4(a0, x0, w0, w1, w2, w3);
    FMA4(a1, x1, w0, w1, w2, w3);
    FMA4(a2, x2, w0, w1, w2, w3);
    FMA4(a3, x3, w0, w1, w2, w3);
  }
  #pragma unroll
  for (int i = 0; i < 4; ++i) {
    if (b + i < nvalid) {
      long n = n0 + b + i;
      float4 a = (i == 0) ? a0 : (i == 1) ? a1 : (i == 2) ? a2 : a3;
      const float4 r4 = *(const float4*)(rp + (long)batch[n] * FO + f0);
      float dn = dinv[n];
      ushort4 o;
      o.x = f2bf((a.x + r4.x) * dn); o.y = f2bf((a.y + r4.y) * dn);
      o.z = f2bf((a.z + r4.z) * dn); o.w = f2bf((a.w + r4.w) * dn);
      *(ushort4*)(ps2 + n * FH + f0) = o;
    }
  }
}

// ---------------- mean-pool ----------------
__global__ __launch_bounds__(64) void k_pool(const ushort_t* __restrict__ r,
                                             const int* __restrict__ batch,
                                             float* __restrict__ out) {
  const int PC = 100;
  int lane = threadIdx.x;
  long n0 = (long)blockIdx.x * PC;
  long n1 = n0 + PC;
  if (n1 > NN) n1 = NN;
  if (n0 >= NN) return;
  float acc = 0.0f;
  int cur = batch[n0];
  for (long n = n0; n < n1; ++n) {
    int g = batch[n];
    if (g != cur) {
      atomicAdd(&out[(long)cur * (FO + FH) + lane], acc);
      acc = 0.0f;
      cur = g;
    }
    acc += bf2f(r[n * FH + lane]);
  }
  atomicAdd(&out[(long)cur * (FO + FH) + lane], acc);
}

// ---------------- finalize ----------------
__global__ void k_final(float* __restrict__ out, const int* __restrict__ gcnt,
                        const int* __restrict__ root_idx, const ushort_t* __restrict__ h1full) {
  int i = blockIdx.x * blockDim.x + threadIdx.x;
  if (i >= NG * FO) return;
  int g = i >> 6, f = i & 63;
  int c = gcnt[g];
  float inv = 1.0f / fmaxf((float)c, 1.0f);
  out[g * (FO + FH) + f] *= inv;
  out[g * (FO + FH) + FO + f] = (c > 0) ? bf2f(h1full[(long)root_idx[g] * FH + f]) : 0.0f;
}

extern "C" void kernel_launch(void* const* d_in, const int* in_sizes, int n_in,
                              void* d_out, int out_size, void* d_ws, size_t ws_size,
                              hipStream_t stream) {
  const float* x   = (const float*)d_in[0];
  const int*   ei  = (const int*)d_in[1];
  const int*   bat = (const int*)d_in[2];
  const float* W1  = (const float*)d_in[3];
  const float* b1  = (const float*)d_in[4];
  const float* W2  = (const float*)d_in[5];
  const float* b2  = (const float*)d_in[6];
  float* out = (float*)d_out;

  char* p = (char*)d_ws;
  auto carve = [&](size_t bytes) -> void* {
    char* q = p;
    p += (bytes + 511) & ~size_t(511);
    return (void*)q;
  };
  float* dinv    = (float*)carve((size_t)NN * 4);
  int*   pcur    = (int*)carve((size_t)NP * 4);
  int*   part_e  = (int*)carve((size_t)NP * ECAP * 4);
  int*   rowptr  = (int*)carve((size_t)NN * 4);
  int*   rend    = (int*)carve((size_t)NN * 4);
  int*   csr_src = (int*)carve((size_t)NP * ECAP * 4);
  ushort_t* psA  = (ushort_t*)carve((size_t)NN * FH * 2);
  ushort_t* psB  = (ushort_t*)carve((size_t)NN * FH * 2);
  ushort_t* bufB = (ushort_t*)carve((size_t)NN * FH * 2);
  ushort_t* bufD = (ushort_t*)carve((size_t)NN * FH * 2);
  int*   root_i  = (int*)carve((size_t)NG * 4);
  int*   gcnt    = (int*)carve((size_t)NG * 4);
  float* rp      = (float*)carve((size_t)NG * FO * 4);

  const int GB = (NN + 63) / 64;  // 1563
  k_init<<<96, 256, 0, stream>>>(pcur, out, bat, root_i, gcnt);
  k_pscatter<<<256, 1024, 0, stream>>>(ei, pcur, part_e);
  k_psort<<<NP, 256, 0, stream>>>(part_e, pcur, rowptr, rend, dinv, csr_src);
  k_gemm1<<<GB, 256, 0, stream>>>(x, W1, dinv, psA);
  k_rootproj<<<NG, 64, 0, stream>>>(x, W2, root_i, rp);
  k_agg<0><<<NN / 4, 256, 0, stream>>>(psA, dinv, rowptr, rend, csr_src, b1, bufB);
  k_gemm2<<<GB, 256, 0, stream>>>(bufB, W2, rp, bat, dinv, psB);
  k_agg<1><<<NN / 4, 256, 0, stream>>>(psB, dinv, rowptr, rend, csr_src, b2, bufD);
  k_pool<<<(NN + 99) / 100, 64, 0, stream>>>(bufD, bat, out);
  k_final<<<(NG * FO + 255) / 256, 256, 0, stream>>>(out, gcnt, root_i, bufB);
}

// Round 12
// 271.349 us; speedup vs baseline: 1.6706x; 1.0181x over previous
//
#include <hip/hip_runtime.h>
#include <hip/hip_bf16.h>

#define NN 100000
#define NE 3200000
#define FIN 128
#define FH 64
#define FO 64
#define NG 128
#define NP 392        // partitions of 256 nodes
#define PSH 8
#define PMASK 255
#define ECAP 9216     // staging capacity per partition (true edges: 8192 +/- 90)
#define OCAP 11264    // padded csr capacity per partition (8192 + 256*7.5 avg pad + margin)
#define XP 132        // padded Xs row (floats)
#define HP 68         // padded Hs row

typedef unsigned short ushort_t;

__device__ __forceinline__ float bf2f(ushort_t u) {
  unsigned v = ((unsigned)u) << 16;
  float f;
  __builtin_memcpy(&f, &v, 4);
  return f;
}
__device__ __forceinline__ ushort_t f2bf(float f) {
  __hip_bfloat16 b = __float2bfloat16(f);
  ushort_t u;
  __builtin_memcpy(&u, &b, 2);
  return u;
}

#define FMA4(a, xv, w0, w1, w2, w3)                          \
  a.x += xv.x * w0.x + xv.y * w1.x + xv.z * w2.x + xv.w * w3.x; \
  a.y += xv.x * w0.y + xv.y * w1.y + xv.z * w2.y + xv.w * w3.y; \
  a.z += xv.x * w0.z + xv.y * w1.z + xv.z * w2.z + xv.w * w3.z; \
  a.w += xv.x * w0.w + xv.y * w1.w + xv.z * w2.w + xv.w * w3.w;

// ---------------- init + root binary search + zero sentinel rows ----------------
__global__ void k_init(int* __restrict__ pcur, float* __restrict__ out,
                       const int* __restrict__ batch, int* __restrict__ root_idx,
                       int* __restrict__ gcnt,
                       ushort_t* __restrict__ psA, ushort_t* __restrict__ psB) {
  int i = blockIdx.x * blockDim.x + threadIdx.x;
  if (i < NP) pcur[i] = 0;
  if (i < NG * (FO + FH)) out[i] = 0.0f;
  if (i < FH) {  // zero the sentinel message row (node NN)
    psA[(long)NN * FH + i] = 0;
    psB[(long)NN * FH + i] = 0;
  }
  if (i < NG) {
    int g = i;
    int lo = 0, hi = NN;
    while (lo < hi) { int m = (lo + hi) >> 1; if (batch[m] < g) lo = m + 1; else hi = m; }
    int a = lo;
    lo = a; hi = NN;
    while (lo < hi) { int m = (lo + hi) >> 1; if (batch[m] < g + 1) lo = m + 1; else hi = m; }
    int b = lo;
    gcnt[g] = b - a;
    root_idx[g] = (b > a) ? a : (NN - 1);
  }
}

// ---------------- two-phase block-local scatter (1024 thr) ----------------
__global__ __launch_bounds__(1024) void k_pscatter(const int* __restrict__ ei,
                                                   int* __restrict__ pcur,
                                                   int* __restrict__ part_e) {
  __shared__ int lbase[NP];
  __shared__ int lcur[NP];
  const int EPB = NE / 256;  // 12500
  int base = blockIdx.x * EPB;
  int tid = threadIdx.x;
  for (int i = tid; i < NP; i += 1024) { lbase[i] = 0; lcur[i] = 0; }
  __syncthreads();
  for (int i = tid; i < EPB; i += 1024) atomicAdd(&lbase[ei[NE + base + i] >> PSH], 1);
  __syncthreads();
  for (int i = tid; i < NP; i += 1024) {
    int c = lbase[i];
    lbase[i] = c ? (i * ECAP + atomicAdd(&pcur[i], c)) : 0;
  }
  __syncthreads();
  for (int i = tid; i < EPB; i += 1024) {
    int s = ei[base + i];
    int d = ei[NE + base + i];
    int p = d >> PSH;
    int pos = atomicAdd(&lcur[p], 1);
    part_e[lbase[p] + pos] = (s << PSH) | (d & PMASK);
  }
}

// ---------------- per-partition LDS counting sort -> PADDED csr (x16) ----------------
// Each node's slot is rounded up to a multiple of 16; pad entries point at the
// zero sentinel row NN, so k_agg runs a single fully-pipelined 16-deep loop.
__global__ __launch_bounds__(256) void k_psort(const int* __restrict__ part_e,
                                               const int* __restrict__ pcur,
                                               int* __restrict__ rowptr,
                                               int* __restrict__ rend,
                                               float* __restrict__ dinv,
                                               int* __restrict__ csr_src) {
  __shared__ int ew[ECAP];    // 36 KB
  __shared__ int cnt[256];
  __shared__ int pref[256];
  int p = blockIdx.x, tid = threadIdx.x;
  int pb = p * ECAP;
  int ob = p * OCAP;
  int m = pcur[p];
  for (int i = tid; i < m; i += 256) ew[i] = part_e[pb + i];
  cnt[tid] = 0;
  __syncthreads();
  for (int i = tid; i < m; i += 256) atomicAdd(&cnt[ew[i] & PMASK], 1);
  __syncthreads();
  int deg = cnt[tid];
  int pc = (deg + 15) & ~15;   // padded slot size
  pref[tid] = pc;
  __syncthreads();
  for (int d = 1; d < 256; d <<= 1) {
    int t = (tid >= d) ? pref[tid - d] : 0;
    __syncthreads();
    pref[tid] += t;
    __syncthreads();
  }
  int excl = pref[tid] - pc;   // padded exclusive prefix
  int n = (p << PSH) + tid;
  if (n < NN) {
    rowptr[n] = ob + excl;
    rend[n] = ob + excl + pc;  // padded end (multiple of 16)
    dinv[n] = rsqrtf((float)deg + 1.0f);
  }
  // pad-fill this node's tail with sentinel
  for (int j = deg; j < pc; ++j) csr_src[ob + excl + j] = NN;
  __syncthreads();
  pref[tid] = excl;  // scatter cursor
  __syncthreads();
  for (int i = tid; i < m; i += 256) {
    int w = ew[i];
    int pos = atomicAdd(&pref[w & PMASK], 1);
    csr_src[ob + pos] = w >> PSH;
  }
}

// ---------------- GEMM1: ps1 = bf16((x @ W1) * dinv) ; 64-node tile, 4x4/thread ----------------
__global__ __launch_bounds__(256) void k_gemm1(const float* __restrict__ x,
                                               const float* __restrict__ W1,
                                               const float* __restrict__ dinv,
                                               ushort_t* __restrict__ ps) {
  __shared__ float Xs[64 * XP];    // 33 KB
  __shared__ float Ws[FIN * FH];   // 32 KB
  int tid = threadIdx.x;
  long n0 = (long)blockIdx.x * 64;
  int nvalid = (int)(NN - n0);
  {
    const float4* wg = (const float4*)W1;
    float4* ws4 = (float4*)Ws;
    for (int i = tid; i < FIN * FH / 4; i += 256) ws4[i] = wg[i];
  }
  {
    const float4* xg = (const float4*)(x + n0 * FIN);
    for (int i = tid; i < 64 * 32; i += 256) {
      int r = i >> 5, c = i & 31;
      if (r < nvalid) *(float4*)&Xs[r * XP + c * 4] = xg[(long)r * 32 + c];
    }
  }
  __syncthreads();
  int fg = tid & 15, ng = tid >> 4;
  int f0 = fg * 4, b = ng * 4;
  float4 a0 = {0, 0, 0, 0}, a1 = a0, a2 = a0, a3 = a0;
  #pragma unroll 8
  for (int k = 0; k < FIN; k += 4) {
    float4 x0 = *(const float4*)&Xs[(b + 0) * XP + k];
    float4 x1 = *(const float4*)&Xs[(b + 1) * XP + k];
    float4 x2 = *(const float4*)&Xs[(b + 2) * XP + k];
    float4 x3 = *(const float4*)&Xs[(b + 3) * XP + k];
    float4 w0 = *(const float4*)&Ws[(k + 0) * FH + f0];
    float4 w1 = *(const float4*)&Ws[(k + 1) * FH + f0];
    float4 w2 = *(const float4*)&Ws[(k + 2) * FH + f0];
    float4 w3 = *(const float4*)&Ws[(k + 3) * FH + f0];
    FMA4(a0, x0, w0, w1, w2, w3);
    FMA4(a1, x1, w0, w1, w2, w3);
    FMA4(a2, x2, w0, w1, w2, w3);
    FMA4(a3, x3, w0, w1, w2, w3);
  }
  #pragma unroll
  for (int i = 0; i < 4; ++i) {
    if (b + i < nvalid) {
      float4 a = (i == 0) ? a0 : (i == 1) ? a1 : (i == 2) ? a2 : a3;
      float dn = dinv[n0 + b + i];
      ushort4 o;
      o.x = f2bf(a.x * dn); o.y = f2bf(a.y * dn);
      o.z = f2bf(a.z * dn); o.w = f2bf(a.w * dn);
      *(ushort4*)(ps + (n0 + b + i) * FH + f0) = o;
    }
  }
}

// ---------------- per-graph root projection ----------------
__global__ __launch_bounds__(64) void k_rootproj(const float* __restrict__ x,
                                                 const float* __restrict__ W2,
                                                 const int* __restrict__ root_idx,
                                                 float* __restrict__ rp) {
  __shared__ float xr[FIN];
  int g = blockIdx.x;
  int t = threadIdx.x;
  long r = root_idx[g];
  xr[t]      = fmaxf(x[r * FIN + t], 0.0f);
  xr[t + 64] = fmaxf(x[r * FIN + t + 64], 0.0f);
  __syncthreads();
  float acc = 0.0f;
  #pragma unroll 8
  for (int i = 0; i < FIN; ++i) acc += xr[i] * W2[(FH + i) * FO + t];
  rp[g * FO + t] = acc;
}

// ---------------- per-node aggregation: single 16-deep loop over padded edges ----------------
template <int RELU>
__global__ __launch_bounds__(256) void k_agg(const ushort_t* __restrict__ ps,
                                             const float* __restrict__ dinv,
                                             const int* __restrict__ rowptr,
                                             const int* __restrict__ rend,
                                             const int* __restrict__ csr_src,
                                             const float* __restrict__ bias,
                                             ushort_t* __restrict__ outb) {
  int lane = threadIdx.x & 63;
  int n = __builtin_amdgcn_readfirstlane(blockIdx.x * 4 + (threadIdx.x >> 6));
  int beg = __builtin_amdgcn_readfirstlane(rowptr[n]);
  int end = __builtin_amdgcn_readfirstlane(rend[n]);  // beg + multiple of 16
  float acc = bf2f(ps[((long)n << 6) + lane]);
  for (int i = beg; i < end; i += 16) {
    int s0 = __builtin_amdgcn_readfirstlane(csr_src[i + 0]);
    int s1 = __builtin_amdgcn_readfirstlane(csr_src[i + 1]);
    int s2 = __builtin_amdgcn_readfirstlane(csr_src[i + 2]);
    int s3 = __builtin_amdgcn_readfirstlane(csr_src[i + 3]);
    int s4 = __builtin_amdgcn_readfirstlane(csr_src[i + 4]);
    int s5 = __builtin_amdgcn_readfirstlane(csr_src[i + 5]);
    int s6 = __builtin_amdgcn_readfirstlane(csr_src[i + 6]);
    int s7 = __builtin_amdgcn_readfirstlane(csr_src[i + 7]);
    int s8 = __builtin_amdgcn_readfirstlane(csr_src[i + 8]);
    int s9 = __builtin_amdgcn_readfirstlane(csr_src[i + 9]);
    int sa = __builtin_amdgcn_readfirstlane(csr_src[i + 10]);
    int sb = __builtin_amdgcn_readfirstlane(csr_src[i + 11]);
    int sc = __builtin_amdgcn_readfirstlane(csr_src[i + 12]);
    int sd = __builtin_amdgcn_readfirstlane(csr_src[i + 13]);
    int se = __builtin_amdgcn_readfirstlane(csr_src[i + 14]);
    int sf = __builtin_amdgcn_readfirstlane(csr_src[i + 15]);
    float v0 = bf2f(ps[((long)s0 << 6) + lane]);
    float v1 = bf2f(ps[((long)s1 << 6) + lane]);
    float v2 = bf2f(ps[((long)s2 << 6) + lane]);
    float v3 = bf2f(ps[((long)s3 << 6) + lane]);
    float v4 = bf2f(ps[((long)s4 << 6) + lane]);
    float v5 = bf2f(ps[((long)s5 << 6) + lane]);
    float v6 = bf2f(ps[((long)s6 << 6) + lane]);
    float v7 = bf2f(ps[((long)s7 << 6) + lane]);
    float v8 = bf2f(ps[((long)s8 << 6) + lane]);
    float v9 = bf2f(ps[((long)s9 << 6) + lane]);
    float va = bf2f(ps[((long)sa << 6) + lane]);
    float vb = bf2f(ps[((long)sb << 6) + lane]);
    float vc = bf2f(ps[((long)sc << 6) + lane]);
    float vd = bf2f(ps[((long)sd << 6) + lane]);
    float ve = bf2f(ps[((long)se << 6) + lane]);
    float vf = bf2f(ps[((long)sf << 6) + lane]);
    acc += v0; acc += v1; acc += v2; acc += v3;
    acc += v4; acc += v5; acc += v6; acc += v7;
    acc += v8; acc += v9; acc += va; acc += vb;
    acc += vc; acc += vd; acc += ve; acc += vf;
  }
  float val = dinv[n] * acc + bias[lane];
  if (RELU) val = fmaxf(val, 0.0f);
  outb[((long)n << 6) + lane] = f2bf(val);
}

// ---------------- GEMM2: 64-node tile, 4x4/thread ----------------
__global__ __launch_bounds__(256) void k_gemm2(const ushort_t* __restrict__ h1,
                                               const float* __restrict__ W2,
                                               const float* __restrict__ rp,
                                               const int* __restrict__ batch,
                                               const float* __restrict__ dinv,
                                               ushort_t* __restrict__ ps2) {
  __shared__ float Hs[64 * HP];    // 17 KB
  __shared__ float Ws[FH * FO];    // 16 KB
  int tid = threadIdx.x;
  long n0 = (long)blockIdx.x * 64;
  int nvalid = (int)(NN - n0);
  {
    const float4* wg = (const float4*)W2;
    float4* ws4 = (float4*)Ws;
    for (int i = tid; i < FH * FO / 4; i += 256) ws4[i] = wg[i];
  }
  {
    for (int i = tid; i < 64 * 16; i += 256) {
      int r = i >> 4, c = i & 15;
      if (r < nvalid) {
        ushort4 v = *(const ushort4*)(h1 + (n0 + r) * FH + c * 4);
        float4 f;
        f.x = fmaxf(bf2f(v.x), 0.f); f.y = fmaxf(bf2f(v.y), 0.f);
        f.z = fmaxf(bf2f(v.z), 0.f); f.w = fmaxf(bf2f(v.w), 0.f);
        *(float4*)&Hs[r * HP + c * 4] = f;
      }
    }
  }
  __syncthreads();
  int fg = tid & 15, ng = tid >> 4;
  int f0 = fg * 4, b = ng * 4;
  float4 a0 = {0, 0, 0, 0}, a1 = a0, a2 = a0, a3 = a0;
  #pragma unroll 8
  for (int k = 0; k < FH; k += 4) {
    float4 x0 = *(const float4*)&Hs[(b + 0) * HP + k];
    float4 x1 = *(const float4*)&Hs[(b + 1) * HP + k];
    float4 x2 = *(const float4*)&Hs[(b + 2) * HP + k];
    float4 x3 = *(const float4*)&Hs[(b + 3) * HP + k];
    float4 w0 = *(const float4*)&Ws[(k + 0) * FO + f0];
    float4 w1 = *(const float4*)&Ws[(k + 1) * FO + f0];
    float4 w2 = *(const float4*)&Ws[(k + 2) * FO + f0];
    float4 w3 = *(const float4*)&Ws[(k + 3) * FO + f0];
    FMA4(a0, x0, w0, w1, w2, w3);
    FMA4(a1, x1, w0, w1, w2, w3);
    FMA4(a2, x2, w0, w1, w2, w3);
    FMA4(a3, x3, w0, w1, w2, w3);
  }
  #pragma unroll
  for (int i = 0; i < 4; ++i) {
    if (b + i < nvalid) {
      long n = n0 + b + i;
      float4 a = (i == 0) ? a0 : (i == 1) ? a1 : (i == 2) ? a2 : a3;
      const float4 r4 = *(const float4*)(rp + (long)batch[n] * FO + f0);
      float dn = dinv[n];
      ushort4 o;
      o.x = f2bf((a.x + r4.x) * dn); o.y = f2bf((a.y + r4.y) * dn);
      o.z = f2bf((a.z + r4.z) * dn); o.w = f2bf((a.w + r4.w) * dn);
      *(ushort4*)(ps2 + n * FH + f0) = o;
    }
  }
}

// ---------------- mean-pool ----------------
__global__ __launch_bounds__(64) void k_pool(const ushort_t* __restrict__ r,
                                             const int* __restrict__ batch,
                                             float* __restrict__ out) {
  const int PC = 100;
  int lane = threadIdx.x;
  long n0 = (long)blockIdx.x * PC;
  long n1 = n0 + PC;
  if (n1 > NN) n1 = NN;
  if (n0 >= NN) return;
  float acc = 0.0f;
  int cur = batch[n0];
  for (long n = n0; n < n1; ++n) {
    int g = batch[n];
    if (g != cur) {
      atomicAdd(&out[(long)cur * (FO + FH) + lane], acc);
      acc = 0.0f;
      cur = g;
    }
    acc += bf2f(r[n * FH + lane]);
  }
  atomicAdd(&out[(long)cur * (FO + FH) + lane], acc);
}

// ---------------- finalize ----------------
__global__ void k_final(float* __restrict__ out, const int* __restrict__ gcnt,
                        const int* __restrict__ root_idx, const ushort_t* __restrict__ h1full) {
  int i = blockIdx.x * blockDim.x + threadIdx.x;
  if (i >= NG * FO) return;
  int g = i >> 6, f = i & 63;
  int c = gcnt[g];
  float inv = 1.0f / fmaxf((float)c, 1.0f);
  out[g * (FO + FH) + f] *= inv;
  out[g * (FO + FH) + FO + f] = (c > 0) ? bf2f(h1full[(long)root_idx[g] * FH + f]) : 0.0f;
}

extern "C" void kernel_launch(void* const* d_in, const int* in_sizes, int n_in,
                              void* d_out, int out_size, void* d_ws, size_t ws_size,
                              hipStream_t stream) {
  const float* x   = (const float*)d_in[0];
  const int*   ei  = (const int*)d_in[1];
  const int*   bat = (const int*)d_in[2];
  const float* W1  = (const float*)d_in[3];
  const float* b1  = (const float*)d_in[4];
  const float* W2  = (const float*)d_in[5];
  const float* b2  = (const float*)d_in[6];
  float* out = (float*)d_out;

  char* p = (char*)d_ws;
  auto carve = [&](size_t bytes) -> void* {
    char* q = p;
    p += (bytes + 511) & ~size_t(511);
    return (void*)q;
  };
  float* dinv    = (float*)carve((size_t)NN * 4);
  int*   pcur    = (int*)carve((size_t)NP * 4);
  int*   part_e  = (int*)carve((size_t)NP * ECAP * 4);
  int*   rowptr  = (int*)carve((size_t)NN * 4);
  int*   rend    = (int*)carve((size_t)NN * 4);
  int*   csr_src = (int*)carve((size_t)NP * OCAP * 4);
  ushort_t* psA  = (ushort_t*)carve((size_t)(NN + 1) * FH * 2);  // +sentinel row
  ushort_t* psB  = (ushort_t*)carve((size_t)(NN + 1) * FH * 2);  // +sentinel row
  ushort_t* bufB = (ushort_t*)carve((size_t)NN * FH * 2);
  ushort_t* bufD = (ushort_t*)carve((size_t)NN * FH * 2);
  int*   root_i  = (int*)carve((size_t)NG * 4);
  int*   gcnt    = (int*)carve((size_t)NG * 4);
  float* rp      = (float*)carve((size_t)NG * FO * 4);

  const int GB = (NN + 63) / 64;  // 1563
  k_init<<<96, 256, 0, stream>>>(pcur, out, bat, root_i, gcnt, psA, psB);
  k_pscatter<<<256, 1024, 0, stream>>>(ei, pcur, part_e);
  k_psort<<<NP, 256, 0, stream>>>(part_e, pcur, rowptr, rend, dinv, csr_src);
  k_gemm1<<<GB, 256, 0, stream>>>(x, W1, dinv, psA);
  k_rootproj<<<NG, 64, 0, stream>>>(x, W2, root_i, rp);
  k_agg<0><<<NN / 4, 256, 0, stream>>>(psA, dinv, rowptr, rend, csr_src, b1, bufB);
  k_gemm2<<<GB, 256, 0, stream>>>(bufB, W2, rp, bat, dinv, psB);
  k_agg<1><<<NN / 4, 256, 0, stream>>>(psB, dinv, rowptr, rend, csr_src, b2, bufD);
  k_pool<<<(NN + 99) / 100, 64, 0, stream>>>(bufD, bat, out);
  k_final<<<(NG * FO + 255) / 256, 256, 0, stream>>>(out, gcnt, root_i, bufB);
}

// Round 13
// 215.880 us; speedup vs baseline: 2.0998x; 1.2569x over previous
//
#include <hip/hip_runtime.h>
#include <hip/hip_bf16.h>

#define NN 100000
#define NE 3200000
#define FIN 128
#define FH 64
#define FO 64
#define NG 128
#define NP 392        // partitions of 256 nodes
#define PSH 8
#define PMASK 255
#define ECAP 9216     // staging capacity per partition (true edges: 8192 +/- 90)
#define OCAP 11264    // padded csr capacity per partition
#define XPAD 136      // bf16 row pad for K=128 tiles (16B-aligned, 4-bank rotation)
#define HPAD 72       // bf16 row pad for K=64 tiles

typedef unsigned short ushort_t;
typedef __attribute__((ext_vector_type(8))) short bf16x8;
typedef __attribute__((ext_vector_type(4))) float f32x4;

__device__ __forceinline__ float bf2f(ushort_t u) {
  unsigned v = ((unsigned)u) << 16;
  float f;
  __builtin_memcpy(&f, &v, 4);
  return f;
}
__device__ __forceinline__ ushort_t f2bf(float f) {
  __hip_bfloat16 b = __float2bfloat16(f);
  ushort_t u;
  __builtin_memcpy(&u, &b, 2);
  return u;
}

// ---------------- init: cursors, out, sentinels, root search, W transposes ----------------
__global__ void k_init(int* __restrict__ pcur, float* __restrict__ out,
                       const int* __restrict__ batch, int* __restrict__ root_idx,
                       int* __restrict__ gcnt,
                       ushort_t* __restrict__ psA, ushort_t* __restrict__ psB,
                       const float* __restrict__ W1, const float* __restrict__ W2,
                       ushort_t* __restrict__ wt1, ushort_t* __restrict__ wt2) {
  int i = blockIdx.x * blockDim.x + threadIdx.x;
  if (i < NP) pcur[i] = 0;
  if (i < NG * (FO + FH)) out[i] = 0.0f;
  if (i < FH) {  // zero the sentinel message row (node NN)
    psA[(long)NN * FH + i] = 0;
    psB[(long)NN * FH + i] = 0;
  }
  if (i < FH * FIN) {  // wt1[f][k] = bf16(W1[k][f])
    int f = i >> 7, k = i & 127;
    wt1[i] = f2bf(W1[k * FH + f]);
  }
  if (i < FH * FO) {   // wt2[f][k] = bf16(W2[k][f]), rows 0..63 of W2
    int f = i >> 6, k = i & 63;
    wt2[i] = f2bf(W2[k * FO + f]);
  }
  if (i < NG) {
    int g = i;
    int lo = 0, hi = NN;
    while (lo < hi) { int m = (lo + hi) >> 1; if (batch[m] < g) lo = m + 1; else hi = m; }
    int a = lo;
    lo = a; hi = NN;
    while (lo < hi) { int m = (lo + hi) >> 1; if (batch[m] < g + 1) lo = m + 1; else hi = m; }
    int b = lo;
    gcnt[g] = b - a;
    root_idx[g] = (b > a) ? a : (NN - 1);
  }
}

// ---------------- two-phase block-local scatter (1024 thr) ----------------
__global__ __launch_bounds__(1024) void k_pscatter(const int* __restrict__ ei,
                                                   int* __restrict__ pcur,
                                                   int* __restrict__ part_e) {
  __shared__ int lbase[NP];
  __shared__ int lcur[NP];
  const int EPB = NE / 256;  // 12500
  int base = blockIdx.x * EPB;
  int tid = threadIdx.x;
  for (int i = tid; i < NP; i += 1024) { lbase[i] = 0; lcur[i] = 0; }
  __syncthreads();
  for (int i = tid; i < EPB; i += 1024) atomicAdd(&lbase[ei[NE + base + i] >> PSH], 1);
  __syncthreads();
  for (int i = tid; i < NP; i += 1024) {
    int c = lbase[i];
    lbase[i] = c ? (i * ECAP + atomicAdd(&pcur[i], c)) : 0;
  }
  __syncthreads();
  for (int i = tid; i < EPB; i += 1024) {
    int s = ei[base + i];
    int d = ei[NE + base + i];
    int p = d >> PSH;
    int pos = atomicAdd(&lcur[p], 1);
    part_e[lbase[p] + pos] = (s << PSH) | (d & PMASK);
  }
}

// ---------------- per-partition LDS counting sort -> PADDED csr (x16) ----------------
__global__ __launch_bounds__(256) void k_psort(const int* __restrict__ part_e,
                                               const int* __restrict__ pcur,
                                               int* __restrict__ rowptr,
                                               int* __restrict__ rend,
                                               float* __restrict__ dinv,
                                               int* __restrict__ csr_src) {
  __shared__ int ew[ECAP];    // 36 KB
  __shared__ int cnt[256];
  __shared__ int pref[256];
  int p = blockIdx.x, tid = threadIdx.x;
  int pb = p * ECAP;
  int ob = p * OCAP;
  int m = pcur[p];
  for (int i = tid; i < m; i += 256) ew[i] = part_e[pb + i];
  cnt[tid] = 0;
  __syncthreads();
  for (int i = tid; i < m; i += 256) atomicAdd(&cnt[ew[i] & PMASK], 1);
  __syncthreads();
  int deg = cnt[tid];
  int pc = (deg + 15) & ~15;
  pref[tid] = pc;
  __syncthreads();
  for (int d = 1; d < 256; d <<= 1) {
    int t = (tid >= d) ? pref[tid - d] : 0;
    __syncthreads();
    pref[tid] += t;
    __syncthreads();
  }
  int excl = pref[tid] - pc;
  int n = (p << PSH) + tid;
  if (n < NN) {
    rowptr[n] = ob + excl;
    rend[n] = ob + excl + pc;
    dinv[n] = rsqrtf((float)deg + 1.0f);
  }
  for (int j = deg; j < pc; ++j) csr_src[ob + excl + j] = NN;
  __syncthreads();
  pref[tid] = excl;
  __syncthreads();
  for (int i = tid; i < m; i += 256) {
    int w = ew[i];
    int pos = atomicAdd(&pref[w & PMASK], 1);
    csr_src[ob + pos] = w >> PSH;
  }
}

// ---------------- GEMM1 (MFMA): ps1 = bf16((x @ W1) * dinv) ----------------
// Block: 64 nodes x 64 feats. 4 waves, each 16 nodes x 4 f-tiles, K=128 in 4 steps.
__global__ __launch_bounds__(256) void k_gemm1(const float* __restrict__ x,
                                               const ushort_t* __restrict__ wt1,
                                               const float* __restrict__ dinv,
                                               ushort_t* __restrict__ ps) {
  __shared__ ushort_t Xs[64 * XPAD];   // 17.4 KB (bf16 x-tile)
  __shared__ ushort_t Ws[64 * XPAD];   // 17.4 KB (wt1 [f][k])
  int tid = threadIdx.x;
  long n0 = (long)blockIdx.x * 64;
  int nvalid = (int)(NN - n0);
  if (nvalid > 64) nvalid = 64;
  // stage x -> bf16 (rows guarded)
  for (int idx = tid; idx < 64 * 32; idx += 256) {
    int r = idx >> 5, c4 = (idx & 31) * 4;
    if (r < nvalid) {
      float4 v = *(const float4*)(x + (n0 + r) * FIN + c4);
      ushort4 o;
      o.x = f2bf(v.x); o.y = f2bf(v.y); o.z = f2bf(v.z); o.w = f2bf(v.w);
      *(ushort4*)&Xs[r * XPAD + c4] = o;
    }
  }
  // stage wt1
  for (int idx = tid; idx < 64 * 16; idx += 256) {
    int r = idx >> 4, c8 = (idx & 15) * 8;
    *(ushort4*)&Ws[r * XPAD + c8]     = *(const ushort4*)(wt1 + r * FIN + c8);
    *(ushort4*)&Ws[r * XPAD + c8 + 4] = *(const ushort4*)(wt1 + r * FIN + c8 + 4);
  }
  __syncthreads();
  int w = tid >> 6, l = tid & 63;
  int nb = w * 16;
  int arow = l & 15, koff = (l >> 4) * 8;
  f32x4 acc0 = {0.f, 0.f, 0.f, 0.f}, acc1 = acc0, acc2 = acc0, acc3 = acc0;
  #pragma unroll
  for (int ks = 0; ks < 4; ++ks) {
    bf16x8 a  = *(const bf16x8*)&Xs[(nb + arow) * XPAD + ks * 32 + koff];
    bf16x8 b0 = *(const bf16x8*)&Ws[(arow +  0) * XPAD + ks * 32 + koff];
    bf16x8 b1 = *(const bf16x8*)&Ws[(arow + 16) * XPAD + ks * 32 + koff];
    bf16x8 b2 = *(const bf16x8*)&Ws[(arow + 32) * XPAD + ks * 32 + koff];
    bf16x8 b3 = *(const bf16x8*)&Ws[(arow + 48) * XPAD + ks * 32 + koff];
    acc0 = __builtin_amdgcn_mfma_f32_16x16x32_bf16(a, b0, acc0, 0, 0, 0);
    acc1 = __builtin_amdgcn_mfma_f32_16x16x32_bf16(a, b1, acc1, 0, 0, 0);
    acc2 = __builtin_amdgcn_mfma_f32_16x16x32_bf16(a, b2, acc2, 0, 0, 0);
    acc3 = __builtin_amdgcn_mfma_f32_16x16x32_bf16(a, b3, acc3, 0, 0, 0);
  }
  int drow = (l >> 4) * 4, dcol = l & 15;
  #pragma unroll
  for (int j = 0; j < 4; ++j) {
    int r = nb + drow + j;
    if (r < nvalid) {
      long n = n0 + r;
      float dn = dinv[n];
      ps[n * FH +  0 + dcol] = f2bf(acc0[j] * dn);
      ps[n * FH + 16 + dcol] = f2bf(acc1[j] * dn);
      ps[n * FH + 32 + dcol] = f2bf(acc2[j] * dn);
      ps[n * FH + 48 + dcol] = f2bf(acc3[j] * dn);
    }
  }
}

// ---------------- per-graph root projection ----------------
__global__ __launch_bounds__(64) void k_rootproj(const float* __restrict__ x,
                                                 const float* __restrict__ W2,
                                                 const int* __restrict__ root_idx,
                                                 float* __restrict__ rp) {
  __shared__ float xr[FIN];
  int g = blockIdx.x;
  int t = threadIdx.x;
  long r = root_idx[g];
  xr[t]      = fmaxf(x[r * FIN + t], 0.0f);
  xr[t + 64] = fmaxf(x[r * FIN + t + 64], 0.0f);
  __syncthreads();
  float acc = 0.0f;
  #pragma unroll 8
  for (int i = 0; i < FIN; ++i) acc += xr[i] * W2[(FH + i) * FO + t];
  rp[g * FO + t] = acc;
}

// ---------------- per-node aggregation: single 16-deep loop over padded edges ----------------
template <int RELU>
__global__ __launch_bounds__(256) void k_agg(const ushort_t* __restrict__ ps,
                                             const float* __restrict__ dinv,
                                             const int* __restrict__ rowptr,
                                             const int* __restrict__ rend,
                                             const int* __restrict__ csr_src,
                                             const float* __restrict__ bias,
                                             ushort_t* __restrict__ outb) {
  int lane = threadIdx.x & 63;
  int n = __builtin_amdgcn_readfirstlane(blockIdx.x * 4 + (threadIdx.x >> 6));
  int beg = __builtin_amdgcn_readfirstlane(rowptr[n]);
  int end = __builtin_amdgcn_readfirstlane(rend[n]);
  float acc = bf2f(ps[((long)n << 6) + lane]);
  for (int i = beg; i < end; i += 16) {
    int s0 = __builtin_amdgcn_readfirstlane(csr_src[i + 0]);
    int s1 = __builtin_amdgcn_readfirstlane(csr_src[i + 1]);
    int s2 = __builtin_amdgcn_readfirstlane(csr_src[i + 2]);
    int s3 = __builtin_amdgcn_readfirstlane(csr_src[i + 3]);
    int s4 = __builtin_amdgcn_readfirstlane(csr_src[i + 4]);
    int s5 = __builtin_amdgcn_readfirstlane(csr_src[i + 5]);
    int s6 = __builtin_amdgcn_readfirstlane(csr_src[i + 6]);
    int s7 = __builtin_amdgcn_readfirstlane(csr_src[i + 7]);
    int s8 = __builtin_amdgcn_readfirstlane(csr_src[i + 8]);
    int s9 = __builtin_amdgcn_readfirstlane(csr_src[i + 9]);
    int sa = __builtin_amdgcn_readfirstlane(csr_src[i + 10]);
    int sb = __builtin_amdgcn_readfirstlane(csr_src[i + 11]);
    int sc = __builtin_amdgcn_readfirstlane(csr_src[i + 12]);
    int sd = __builtin_amdgcn_readfirstlane(csr_src[i + 13]);
    int se = __builtin_amdgcn_readfirstlane(csr_src[i + 14]);
    int sf = __builtin_amdgcn_readfirstlane(csr_src[i + 15]);
    float v0 = bf2f(ps[((long)s0 << 6) + lane]);
    float v1 = bf2f(ps[((long)s1 << 6) + lane]);
    float v2 = bf2f(ps[((long)s2 << 6) + lane]);
    float v3 = bf2f(ps[((long)s3 << 6) + lane]);
    float v4 = bf2f(ps[((long)s4 << 6) + lane]);
    float v5 = bf2f(ps[((long)s5 << 6) + lane]);
    float v6 = bf2f(ps[((long)s6 << 6) + lane]);
    float v7 = bf2f(ps[((long)s7 << 6) + lane]);
    float v8 = bf2f(ps[((long)s8 << 6) + lane]);
    float v9 = bf2f(ps[((long)s9 << 6) + lane]);
    float va = bf2f(ps[((long)sa << 6) + lane]);
    float vb = bf2f(ps[((long)sb << 6) + lane]);
    float vc = bf2f(ps[((long)sc << 6) + lane]);
    float vd = bf2f(ps[((long)sd << 6) + lane]);
    float ve = bf2f(ps[((long)se << 6) + lane]);
    float vf = bf2f(ps[((long)sf << 6) + lane]);
    acc += v0; acc += v1; acc += v2; acc += v3;
    acc += v4; acc += v5; acc += v6; acc += v7;
    acc += v8; acc += v9; acc += va; acc += vb;
    acc += vc; acc += vd; acc += ve; acc += vf;
  }
  float val = dinv[n] * acc + bias[lane];
  if (RELU) val = fmaxf(val, 0.0f);
  outb[((long)n << 6) + lane] = f2bf(val);
}

// ---------------- GEMM2 (MFMA): ps2 = bf16((relu(h1) @ W2[0:64,:] + rp[batch]) * dinv) ----------------
__global__ __launch_bounds__(256) void k_gemm2(const ushort_t* __restrict__ h1,
                                               const ushort_t* __restrict__ wt2,
                                               const float* __restrict__ rp,
                                               const int* __restrict__ batch,
                                               const float* __restrict__ dinv,
                                               ushort_t* __restrict__ ps2) {
  __shared__ ushort_t Hs[64 * HPAD];   // 9.2 KB (relu(h1) bf16)
  __shared__ ushort_t Ws[64 * HPAD];   // 9.2 KB (wt2 [f][k])
  int tid = threadIdx.x;
  long n0 = (long)blockIdx.x * 64;
  int nvalid = (int)(NN - n0);
  if (nvalid > 64) nvalid = 64;
  // stage relu(h1) bf16 (relu = clear if sign bit set)
  for (int idx = tid; idx < 64 * 16; idx += 256) {
    int r = idx >> 4, c4 = (idx & 15) * 4;
    if (r < nvalid) {
      ushort4 v = *(const ushort4*)(h1 + (n0 + r) * FH + c4);
      ushort4 o;
      o.x = (v.x & 0x8000) ? 0 : v.x;
      o.y = (v.y & 0x8000) ? 0 : v.y;
      o.z = (v.z & 0x8000) ? 0 : v.z;
      o.w = (v.w & 0x8000) ? 0 : v.w;
      *(ushort4*)&Hs[r * HPAD + c4] = o;
    }
  }
  // stage wt2
  for (int idx = tid; idx < 64 * 16; idx += 256) {
    int r = idx >> 4, c4 = (idx & 15) * 4;
    *(ushort4*)&Ws[r * HPAD + c4] = *(const ushort4*)(wt2 + r * FH + c4);
  }
  __syncthreads();
  int w = tid >> 6, l = tid & 63;
  int nb = w * 16;
  int arow = l & 15, koff = (l >> 4) * 8;
  f32x4 acc0 = {0.f, 0.f, 0.f, 0.f}, acc1 = acc0, acc2 = acc0, acc3 = acc0;
  #pragma unroll
  for (int ks = 0; ks < 2; ++ks) {
    bf16x8 a  = *(const bf16x8*)&Hs[(nb + arow) * HPAD + ks * 32 + koff];
    bf16x8 b0 = *(const bf16x8*)&Ws[(arow +  0) * HPAD + ks * 32 + koff];
    bf16x8 b1 = *(const bf16x8*)&Ws[(arow + 16) * HPAD + ks * 32 + koff];
    bf16x8 b2 = *(const bf16x8*)&Ws[(arow + 32) * HPAD + ks * 32 + koff];
    bf16x8 b3 = *(const bf16x8*)&Ws[(arow + 48) * HPAD + ks * 32 + koff];
    acc0 = __builtin_amdgcn_mfma_f32_16x16x32_bf16(a, b0, acc0, 0, 0, 0);
    acc1 = __builtin_amdgcn_mfma_f32_16x16x32_bf16(a, b1, acc1, 0, 0, 0);
    acc2 = __builtin_amdgcn_mfma_f32_16x16x32_bf16(a, b2, acc2, 0, 0, 0);
    acc3 = __builtin_amdgcn_mfma_f32_16x16x32_bf16(a, b3, acc3, 0, 0, 0);
  }
  int drow = (l >> 4) * 4, dcol = l & 15;
  #pragma unroll
  for (int j = 0; j < 4; ++j) {
    int r = nb + drow + j;
    if (r < nvalid) {
      long n = n0 + r;
      float dn = dinv[n];
      long rb = (long)batch[n] * FO;
      ps2[n * FH +  0 + dcol] = f2bf((acc0[j] + rp[rb +  0 + dcol]) * dn);
      ps2[n * FH + 16 + dcol] = f2bf((acc1[j] + rp[rb + 16 + dcol]) * dn);
      ps2[n * FH + 32 + dcol] = f2bf((acc2[j] + rp[rb + 32 + dcol]) * dn);
      ps2[n * FH + 48 + dcol] = f2bf((acc3[j] + rp[rb + 48 + dcol]) * dn);
    }
  }
}

// ---------------- mean-pool (25 nodes per wave) ----------------
__global__ __launch_bounds__(64) void k_pool(const ushort_t* __restrict__ r,
                                             const int* __restrict__ batch,
                                             float* __restrict__ out) {
  const int PC = 25;
  int lane = threadIdx.x;
  long n0 = (long)blockIdx.x * PC;
  long n1 = n0 + PC;
  if (n1 > NN) n1 = NN;
  if (n0 >= NN) return;
  float acc = 0.0f;
  int cur = batch[n0];
  for (long n = n0; n < n1; ++n) {
    int g = batch[n];
    if (g != cur) {
      atomicAdd(&out[(long)cur * (FO + FH) + lane], acc);
      acc = 0.0f;
      cur = g;
    }
    acc += bf2f(r[n * FH + lane]);
  }
  atomicAdd(&out[(long)cur * (FO + FH) + lane], acc);
}

// ---------------- finalize ----------------
__global__ void k_final(float* __restrict__ out, const int* __restrict__ gcnt,
                        const int* __restrict__ root_idx, const ushort_t* __restrict__ h1full) {
  int i = blockIdx.x * blockDim.x + threadIdx.x;
  if (i >= NG * FO) return;
  int g = i >> 6, f = i & 63;
  int c = gcnt[g];
  float inv = 1.0f / fmaxf((float)c, 1.0f);
  out[g * (FO + FH) + f] *= inv;
  out[g * (FO + FH) + FO + f] = (c > 0) ? bf2f(h1full[(long)root_idx[g] * FH + f]) : 0.0f;
}

extern "C" void kernel_launch(void* const* d_in, const int* in_sizes, int n_in,
                              void* d_out, int out_size, void* d_ws, size_t ws_size,
                              hipStream_t stream) {
  const float* x   = (const float*)d_in[0];
  const int*   ei  = (const int*)d_in[1];
  const int*   bat = (const int*)d_in[2];
  const float* W1  = (const float*)d_in[3];
  const float* b1  = (const float*)d_in[4];
  const float* W2  = (const float*)d_in[5];
  const float* b2  = (const float*)d_in[6];
  float* out = (float*)d_out;

  char* p = (char*)d_ws;
  auto carve = [&](size_t bytes) -> void* {
    char* q = p;
    p += (bytes + 511) & ~size_t(511);
    return (void*)q;
  };
  float* dinv    = (float*)carve((size_t)NN * 4);
  int*   pcur    = (int*)carve((size_t)NP * 4);
  int*   part_e  = (int*)carve((size_t)NP * ECAP * 4);
  int*   rowptr  = (int*)carve((size_t)NN * 4);
  int*   rend    = (int*)carve((size_t)NN * 4);
  int*   csr_src = (int*)carve((size_t)NP * OCAP * 4);
  ushort_t* psA  = (ushort_t*)carve((size_t)(NN + 1) * FH * 2);  // +sentinel
  ushort_t* psB  = (ushort_t*)carve((size_t)(NN + 1) * FH * 2);  // +sentinel
  ushort_t* bufB = (ushort_t*)carve((size_t)NN * FH * 2);
  ushort_t* bufD = (ushort_t*)carve((size_t)NN * FH * 2);
  int*   root_i  = (int*)carve((size_t)NG * 4);
  int*   gcnt    = (int*)carve((size_t)NG * 4);
  float* rp      = (float*)carve((size_t)NG * FO * 4);
  ushort_t* wt1  = (ushort_t*)carve((size_t)FH * FIN * 2);
  ushort_t* wt2  = (ushort_t*)carve((size_t)FH * FO * 2);

  const int GB = (NN + 63) / 64;  // 1563
  k_init<<<96, 256, 0, stream>>>(pcur, out, bat, root_i, gcnt, psA, psB, W1, W2, wt1, wt2);
  k_pscatter<<<256, 1024, 0, stream>>>(ei, pcur, part_e);
  k_psort<<<NP, 256, 0, stream>>>(part_e, pcur, rowptr, rend, dinv, csr_src);
  k_gemm1<<<GB, 256, 0, stream>>>(x, wt1, dinv, psA);
  k_rootproj<<<NG, 64, 0, stream>>>(x, W2, root_i, rp);
  k_agg<0><<<NN / 4, 256, 0, stream>>>(psA, dinv, rowptr, rend, csr_src, b1, bufB);
  k_gemm2<<<GB, 256, 0, stream>>>(bufB, wt2, rp, bat, dinv, psB);
  k_agg<1><<<NN / 4, 256, 0, stream>>>(psB, dinv, rowptr, rend, csr_src, b2, bufD);
  k_pool<<<(NN + 24) / 25, 64, 0, stream>>>(bufD, bat, out);
  k_final<<<(NG * FO + 255) / 256, 256, 0, stream>>>(out, gcnt, root_i, bufB);
}